// Round 16
// baseline (1167.527 us; speedup 1.0000x reference)
//
#include <hip/hip_runtime.h>
#include <hip/hip_bf16.h>
#include <hip/hip_fp8.h>

typedef __bf16 bf16;
typedef unsigned char u8;
typedef __attribute__((ext_vector_type(4))) __bf16 bf16x4;
typedef __attribute__((ext_vector_type(8))) __bf16 bf16x8;
typedef __attribute__((ext_vector_type(4))) float f32x4;

static __device__ __forceinline__ f32x4 MFMA16(bf16x8 a, bf16x8 b, f32x4 c) {
  return __builtin_amdgcn_mfma_f32_16x16x32_bf16(a, b, c, 0, 0, 0);
}
static __device__ __forceinline__ f32x4 MFMA8(long a, long b, f32x4 c) {
  return __builtin_amdgcn_mfma_f32_16x16x32_fp8_fp8(a, b, c, 0, 0, 0);
}

__device__ __forceinline__ float sigm(float x) { return 1.0f / (1.0f + __expf(-x)); }
__device__ __forceinline__ float softplus_(float x) {
  return fmaxf(x, 0.0f) + log1pf(__expf(-fabsf(x)));
}
__device__ __forceinline__ u8 to_fp8(float x) {
  __hip_fp8_e4m3 v(x);
  return (u8)v.__x;
}
__device__ __forceinline__ float from_fp8(u8 b) {
  __hip_fp8_e4m3 v;
  v.__x = b;
  return (float)v;
}

__device__ __forceinline__ void gl16(const void* g, char* l) {
  __builtin_amdgcn_global_load_lds(
      (const __attribute__((address_space(1))) char*)g,
      (__attribute__((address_space(3))) char*)l, 16, 0, 0);
}
// write-through (agent-scope) 4B store: bypasses L2, lands at L3 coherence point
__device__ __forceinline__ void st_wt(unsigned* p, unsigned v) {
  __hip_atomic_store(p, v, __ATOMIC_RELAXED, __HIP_MEMORY_SCOPE_AGENT);
}

// ---------------- fused prep: conversions (bf16 + fp8) + h0(fp8) into hbuf[0] ----------------
__global__ void k_prep(const float* __restrict__ whh, const float* __restrict__ wih,
                       const float* __restrict__ act, const float* __restrict__ w1,
                       const float* __restrict__ w2, const float* __restrict__ dw,
                       const float* __restrict__ beliefs, const int* __restrict__ idx_i,
                       u8* __restrict__ Wh8, bf16* __restrict__ Wib,
                       bf16* __restrict__ actb, bf16* __restrict__ w1b,
                       bf16* __restrict__ w2b, bf16* __restrict__ dwb,
                       u8* __restrict__ hbuf) {
  for (int q = blockIdx.x * blockDim.x + threadIdx.x; q < 1994240;
       q += gridDim.x * blockDim.x) {
    if (q < 814592) {
      const float* src;
      bf16* dst;
      int off;
      if (q < 49152)       { src = wih; dst = Wib;  off = q; }
      else if (q < 573440) { src = act; dst = actb; off = q - 49152; }
      else if (q < 589824) { src = w1;  dst = w1b;  off = q - 573440; }
      else if (q < 606208) { src = w2;  dst = w2b;  off = q - 589824; }
      else                 { src = dw;  dst = dwb;  off = q - 606208; }
      float4 v = *(const float4*)&src[(size_t)off << 2];
      bf16x4 o = {(bf16)v.x, (bf16)v.y, (bf16)v.z, (bf16)v.w};
      *(bf16x4*)&dst[(size_t)off << 2] = o;
    } else if (q < 1207808) {
      const int e = (q - 814592) << 2;          // byte offset in h (1B/elem)
      const int n = e >> 18, rest = e & 262143;
      float4 v = *(const float4*)&beliefs[((size_t)idx_i[n] << 18) + rest];
      unsigned w = (unsigned)to_fp8(v.x) | ((unsigned)to_fp8(v.y) << 8) |
                   ((unsigned)to_fp8(v.z) << 16) | ((unsigned)to_fp8(v.w) << 24);
      const int par = (e >> 10) & 1;            // row parity (parity half-swap)
      *(unsigned*)&hbuf[e ^ (par << 3)] = w;
    } else {
      const int off = q - 1207808;
      float4 v = *(const float4*)&whh[(size_t)off << 2];
      unsigned w = (unsigned)to_fp8(v.x) | ((unsigned)to_fp8(v.y) << 8) |
                   ((unsigned)to_fp8(v.z) << 16) | ((unsigned)to_fp8(v.w) << 24);
      const int bo = off << 2;
      const int par = (bo >> 10) & 1;
      *(unsigned*)&Wh8[bo ^ (par << 3)] = w;
    }
  }
}

// ---------------- persistent GRU v3: WT h stores, no fences, LDS-resident own h-tile ----
// Grid 512 coop (2 blocks/CU). Unique fp8 h buffer per step (prewarmed by memset ->
// no HBM write-allocate). Producer h stores are agent-scope (sc1, L2-bypass -> L3):
// consumer L2 never needs invalidation, Wh8/Wib/actb stay L2-resident all 30 steps.
// Sync: per-mt counters, relaxed agent atomics (protocol validated in R13).
// Block's own 96x32 h-tile lives in persistent LDS (hp never re-read from global).
__global__ __launch_bounds__(256, 2) void k_gru_all(
    u8* __restrict__ hbuf,
    const u8* __restrict__ Wh8, const bf16* __restrict__ Wib,
    const bf16* __restrict__ actb,
    const float* __restrict__ b_ih, const float* __restrict__ b_hh,
    const int* __restrict__ idx_i, const int* __restrict__ Kmat,
    bf16* __restrict__ states, int* __restrict__ done) {
  const int pid = blockIdx.x;
  const int xcd = pid & 7;
  const int rg = xcd >> 2;
  const int cgp = xcd & 3;
  const int q = pid >> 3;
  const int mtl = q & 7;
  const int jtl = q >> 3;
  const int m0 = rg * 768 + mtl * 96;
  const int j0 = (cgp * 8 + jtl) * 32;
  const int mtIdx = rg * 8 + mtl;

  int mk;
  {
    const int nlo = m0 >> 8, nhi = (m0 + 95) >> 8;
    mk = max(max(Kmat[nlo * 4 + 0], Kmat[nlo * 4 + 1]),
             max(Kmat[nlo * 4 + 2], Kmat[nlo * 4 + 3]));
    if (nhi != nlo)
      mk = max(mk, max(max(Kmat[nhi * 4 + 0], Kmat[nhi * 4 + 1]),
                       max(Kmat[nhi * 4 + 2], Kmat[nhi * 4 + 3])));
  }

  const int tid = threadIdx.x, wave = tid >> 6, lane = tid & 63;
  const int l15 = lane & 15;
  const int kgrp = lane >> 4;
  const int wm = wave >> 1;
  const int wj = wave & 1;
  const int jlane = j0 + wj * 16 + l15;

  __shared__ alignas(16) char As[3 * 12288];
  __shared__ alignas(16) char Bs[3 * 12288];
  __shared__ alignas(16) u8 HpL[96 * 40];      // persistent own h-tile (logical order)

  const int srow = lane >> 3;
  int a8off[3], b8off[3], aibase[3], bioff[3];
#pragma unroll
  for (int i = 0; i < 3; ++i) {
    const int r = wave * 24 + i * 8 + srow;
    const int grow = m0 + r;
    a8off[i] = grow * 1024 + ((((lane & 7) ^ ((r >> 1) & 7)) << 4));
    const int wr = (r >> 5) * 1024 + j0 + (r & 31);
    b8off[i] = wr * 1024 + ((((lane & 7) ^ ((r >> 1) & 7)) << 4));
    const int scol = (((lane & 7) ^ srow) << 3);
    const int np = grow >> 8;
    aibase[i] = (idx_i[np] * 256 + (grow & 255)) * 64 + scol;
    bioff[i] = wr * 64 + scol;
  }

  const float br = b_ih[jlane] + b_hh[jlane];
  const float bz = b_ih[1024 + jlane] + b_hh[1024 + jlane];
  const float bin = b_ih[2048 + jlane];
  const float bhn = b_hh[2048 + jlane];

  const int keyA = ((wm * 48 + l15) >> 1) & 7;
  const int keyB = ((wj * 16 + l15) >> 1) & 7;
  const int pa = (l15 & 1) << 3;

  // ---- hp init from hbuf[0] into persistent LDS ----
  {
    unsigned hv[3];
#pragma unroll
    for (int it2 = 0; it2 < 3; ++it2) {
      const int u = it2 * 256 + tid;
      const int row = u >> 3, c = u & 7;
      const int cs = c ^ ((row & 1) << 1);
      hv[it2] = *(const unsigned*)(hbuf + (size_t)(m0 + row) * 1024 + j0 + cs * 4);
    }
    asm volatile("s_waitcnt vmcnt(0)" ::: "memory");
#pragma unroll
    for (int it2 = 0; it2 < 3; ++it2) {
      const int u = it2 * 256 + tid;
      const int row = u >> 3, c = u & 7;
      *(unsigned*)&HpL[row * 40 + c * 4] = hv[it2];
    }
  }
  __syncthreads();

  f32x4 accR[3], accZ[3], accNh[3], accNi[3];
  const f32x4 zero = {0.f, 0.f, 0.f, 0.f};

  for (int s = 0; s <= mk; ++s) {
    const u8* hs = hbuf + (size_t)s * 1572864u;
    u8* hn = hbuf + (size_t)(s + 1) * 1572864u;

    auto stageB = [&](int buf, int slot) {
      char* bd = Bs + buf * 12288 + (wave * 24) * 128;
      if (slot < 8) {
#pragma unroll
        for (int i = 0; i < 3; ++i) gl16(Wh8 + b8off[i] + slot * 128, bd + i * 1024);
      } else {
#pragma unroll
        for (int i = 0; i < 3; ++i) gl16(Wib + bioff[i], bd + i * 1024);
      }
    };
    auto stageA = [&](int buf, int slot) {
      char* ad = As + buf * 12288 + (wave * 24) * 128;
      if (slot < 8) {
#pragma unroll
        for (int i = 0; i < 3; ++i) gl16(hs + a8off[i] + slot * 128, ad + i * 1024);
      } else {
#pragma unroll
        for (int i = 0; i < 3; ++i) gl16(actb + aibase[i] + s * 16384, ad + i * 1024);
      }
    };

    // overlap flag-wait with B-panel staging (B independent of h)
    stageB(0, 0);
    stageB(1, 1);
    if (s > 0) {
      if (tid == 0) {
        int guard = 0;
        while (__hip_atomic_load(&done[(s - 1) * 16 + mtIdx], __ATOMIC_RELAXED,
                                 __HIP_MEMORY_SCOPE_AGENT) < 32) {
          __builtin_amdgcn_s_sleep(1);
          if (++guard > (1 << 22)) break;   // fail-fast, never hang
        }
      }
      __syncthreads();
    }
    stageA(0, 0);
    stageA(1, 1);

#pragma unroll
    for (int f = 0; f < 3; ++f) { accR[f] = zero; accZ[f] = zero; accNh[f] = zero; accNi[f] = zero; }

    auto computeF8 = [&](int buf) {
      const char* ab = As + buf * 12288;
      const char* bb = Bs + buf * 12288;
      const int ra = wm * 48 + l15;
      const int rb = wj * 16 + l15;
#pragma unroll
      for (int kkI = 0; kkI < 4; ++kkI) {
        const int hi = kkI * 2 + (kgrp >> 1);
        const int lo = (kgrp & 1) << 3;
        const int offA = ((((hi ^ keyA) << 4) | lo) ^ pa);
        const int offB = ((((hi ^ keyB) << 4) | lo) ^ pa);
        long a0 = *(const long*)(ab + ra * 128 + offA);
        long a1 = *(const long*)(ab + (ra + 16) * 128 + offA);
        long a2 = *(const long*)(ab + (ra + 32) * 128 + offA);
        long b0 = *(const long*)(bb + rb * 128 + offB);
        long b1 = *(const long*)(bb + (rb + 32) * 128 + offB);
        long b2 = *(const long*)(bb + (rb + 64) * 128 + offB);
        accR[0] = MFMA8(a0, b0, accR[0]);
        accR[1] = MFMA8(a1, b0, accR[1]);
        accR[2] = MFMA8(a2, b0, accR[2]);
        accZ[0] = MFMA8(a0, b1, accZ[0]);
        accZ[1] = MFMA8(a1, b1, accZ[1]);
        accZ[2] = MFMA8(a2, b1, accZ[2]);
        accNh[0] = MFMA8(a0, b2, accNh[0]);
        accNh[1] = MFMA8(a1, b2, accNh[1]);
        accNh[2] = MFMA8(a2, b2, accNh[2]);
      }
    };
    auto computeGi = [&]() {
      const char* ab = As + 2 * 12288;
      const char* bb = Bs + 2 * 12288;
#pragma unroll
      for (int kkI = 0; kkI < 2; ++kkI) {
        const int kbyte = (((kkI << 5) + (kgrp << 3)) << 1) ^ ((l15 & 7) << 4);
        bf16x8 a0 = *(const bf16x8*)(ab + (wm * 48 + l15) * 128 + kbyte);
        bf16x8 a1 = *(const bf16x8*)(ab + (wm * 48 + 16 + l15) * 128 + kbyte);
        bf16x8 a2 = *(const bf16x8*)(ab + (wm * 48 + 32 + l15) * 128 + kbyte);
        bf16x8 b_r = *(const bf16x8*)(bb + (wj * 16 + l15) * 128 + kbyte);
        bf16x8 b_z = *(const bf16x8*)(bb + (32 + wj * 16 + l15) * 128 + kbyte);
        bf16x8 b_n = *(const bf16x8*)(bb + (64 + wj * 16 + l15) * 128 + kbyte);
        accR[0] = MFMA16(a0, b_r, accR[0]);
        accR[1] = MFMA16(a1, b_r, accR[1]);
        accR[2] = MFMA16(a2, b_r, accR[2]);
        accZ[0] = MFMA16(a0, b_z, accZ[0]);
        accZ[1] = MFMA16(a1, b_z, accZ[1]);
        accZ[2] = MFMA16(a2, b_z, accZ[2]);
        accNi[0] = MFMA16(a0, b_n, accNi[0]);
        accNi[1] = MFMA16(a1, b_n, accNi[1]);
        accNi[2] = MFMA16(a2, b_n, accNi[2]);
      }
    };

#pragma unroll
    for (int t = 0; t < 9; ++t) {
      if (t < 7) { stageA((t + 2) % 3, t + 2); stageB((t + 2) % 3, t + 2); }
      // batches: B0,B1,A0,A1 then AB2.. -> t=0 needs vmcnt(9); t in 1..6: 12; 7: 6; 8: 0
      if (t == 0)      asm volatile("s_waitcnt vmcnt(9)" ::: "memory");
      else if (t <= 6) asm volatile("s_waitcnt vmcnt(12)" ::: "memory");
      else if (t == 7) asm volatile("s_waitcnt vmcnt(6)" ::: "memory");
      else             asm volatile("s_waitcnt vmcnt(0)" ::: "memory");
      __builtin_amdgcn_s_barrier();
      if (t == 8) computeGi();
      else        computeF8(t % 3);
      __builtin_amdgcn_sched_barrier(0);
      __builtin_amdgcn_s_barrier();
    }

    // ---- epilogue: gates from persistent LDS hp (in-place update) ----
    bf16* Hn = (bf16*)Bs;   // bf16 transpose tile for states (Bs buf0 dead)
#pragma unroll
    for (int mf = 0; mf < 3; ++mf) {
#pragma unroll
      for (int ii = 0; ii < 4; ++ii) {
        const int ml = wm * 48 + mf * 16 + kgrp * 4 + ii;
        const int jl = wj * 16 + l15;
        float hp = from_fp8(HpL[ml * 40 + jl]);
        float rg2 = sigm(accR[mf][ii] + br);
        float zg = sigm(accZ[mf][ii] + bz);
        float ng = tanhf(accNi[mf][ii] + bin + rg2 * (accNh[mf][ii] + bhn));
        float hnew = (1.0f - zg) * ng + zg * hp;
        HpL[ml * 40 + jl] = to_fp8(hnew);     // in-place: same thread owns (ml,jl)
        Hn[ml * 40 + jl] = (bf16)hnew;
      }
    }
    __syncthreads();

    // h out: write-through (agent) stores; states: normal stores (c*4 chunk fix)
#pragma unroll
    for (int it2 = 0; it2 < 3; ++it2) {
      const int u = it2 * 256 + tid;
      const int row = u >> 3, c = u & 7;
      const int cs = c ^ ((row & 1) << 1);
      st_wt((unsigned*)(hn + (size_t)(m0 + row) * 1024 + j0 + cs * 4),
            *(const unsigned*)&HpL[row * 40 + c * 4]);
      const int m = m0 + row;
      const int n = m >> 8;
      const int b = m & 255;
#pragma unroll
      for (int g = 0; g < 4; ++g) {
        if (Kmat[n * 4 + g] == s) {
          uint2 v;
          v.x = *(const unsigned*)&Hn[row * 40 + c * 4];
          v.y = *(const unsigned*)&Hn[row * 40 + c * 4 + 2];
          *(uint2*)&states[((size_t)(n * 4 + g) * 256 + b) * 1024 + j0 + c * 4] = v;
        }
      }
    }

    asm volatile("s_waitcnt vmcnt(0)" ::: "memory");
    __syncthreads();
    if (tid == 0)
      __hip_atomic_fetch_add(&done[s * 16 + mtIdx], 1, __ATOMIC_RELAXED,
                             __HIP_MEMORY_SCOPE_AGENT);
  }
}

// ---------------- generic GEMM: C = A(M x K) @ W(N x K)^T, fused epilogues ----------------
template <int EPI, int SWZ>
__global__ __launch_bounds__(256) void k_gemm_epi(
    const bf16* __restrict__ A, const bf16* __restrict__ W, int K, int Nreal, int ld_out,
    const float* __restrict__ bias, const bf16* __restrict__ resid,
    float* __restrict__ outF, bf16* __restrict__ outB) {
  int mt, jt;
  if (SWZ) {
    const int lin = blockIdx.x;
    const int x = lin & 7, k = lin >> 3;
    mt = 12 * x + k % 12;
    jt = k / 12;
  } else {
    mt = blockIdx.x;
    jt = blockIdx.y;
  }
  const int m0 = mt * 64;
  const int j0 = jt * 64;
  const int tid = threadIdx.x, wave = tid >> 6, lane = tid & 63;
  __shared__ alignas(16) bf16 Al[64][72];
  __shared__ alignas(16) bf16 Wl[64][72];

  f32x4 acc[4];
  const f32x4 zero = {0.f, 0.f, 0.f, 0.f};
#pragma unroll
  for (int f = 0; f < 4; ++f) acc[f] = zero;

  const int r = tid >> 3, c8 = (tid & 7) << 3;
  const int arow = wave * 16 + (lane & 15);
  const int koff = (lane >> 4) << 3;

  for (int kb = 0; kb < K; kb += 64) {
    *(bf16x8*)&Al[r][c8]      = *(const bf16x8*)&A[(size_t)(m0 + r) * K + kb + c8];
    *(bf16x8*)&Al[r + 32][c8] = *(const bf16x8*)&A[(size_t)(m0 + r + 32) * K + kb + c8];
    int jr = j0 + r;      if (jr >= Nreal) jr = Nreal - 1;
    int jr2 = j0 + r + 32; if (jr2 >= Nreal) jr2 = Nreal - 1;
    *(bf16x8*)&Wl[r][c8]      = *(const bf16x8*)&W[(size_t)jr * K + kb + c8];
    *(bf16x8*)&Wl[r + 32][c8] = *(const bf16x8*)&W[(size_t)jr2 * K + kb + c8];
    __syncthreads();
#pragma unroll
    for (int kk = 0; kk < 64; kk += 32) {
      bf16x8 av = *(const bf16x8*)&Al[arow][kk + koff];
#pragma unroll
      for (int nf = 0; nf < 4; ++nf) {
        acc[nf] = MFMA16(av, *(const bf16x8*)&Wl[nf * 16 + (lane & 15)][kk + koff], acc[nf]);
      }
    }
    __syncthreads();
  }

#pragma unroll
  for (int nf = 0; nf < 4; ++nf) {
    int j = j0 + nf * 16 + (lane & 15);
    float bj = (j < Nreal) ? bias[j] : 0.f;
#pragma unroll
    for (int i = 0; i < 4; ++i) {
      int m = m0 + wave * 16 + ((lane >> 4) << 2) + i;
      float v = acc[nf][i] + bj;
      if (EPI == 0) {
        outB[(size_t)m * ld_out + j] = (bf16)fmaxf(v, 0.f);
      } else if (EPI == 1) {
        v = fmaxf(v, 0.f) + (float)resid[(size_t)m * ld_out + j];
        outB[(size_t)m * ld_out + j] = (bf16)v;
      } else {
        if (j < Nreal) outF[(size_t)m * ld_out + j] = v;
      }
    }
  }
}

// ---------------- loss: one wave per (row, player-head) ----------------
__global__ __launch_bounds__(256) void k_loss_wave(
    const float* __restrict__ logits, const float* __restrict__ obs,
    const int* __restrict__ idx_i, const int* __restrict__ Kmat,
    float* __restrict__ partials) {
  const int gw = blockIdx.x * 4 + (threadIdx.x >> 6);
  const int lane = threadIdx.x & 63;
  const int row = gw >> 1, p = gw & 1;
  const int n = row >> 10, g = (row >> 8) & 3, b = row & 255;
  const int i = idx_i[n], k = Kmat[n * 4 + g];
  const float* Lp = logits + (size_t)row * 814 + p * 407;
  const float* tg = obs + ((size_t)(k + i + 1) * 256 + b) * 16 + p * 8;

  float v[7];
#pragma unroll
  for (int it = 0; it < 7; ++it) {
    const int c = lane + it * 64;
    v[it] = (c < 400) ? Lp[c] : -1e30f;
  }
  float mx = fmaxf(fmaxf(fmaxf(v[0], v[1]), fmaxf(v[2], v[3])),
                   fmaxf(fmaxf(v[4], v[5]), v[6]));
#pragma unroll
  for (int s = 32; s; s >>= 1) mx = fmaxf(mx, __shfl_xor(mx, s));
  float se = 0.f;
#pragma unroll
  for (int it = 0; it < 7; ++it) {
    const int c = lane + it * 64;
    se += (c < 400) ? __expf(v[it] - mx) : 0.f;
  }
#pragma unroll
  for (int s = 32; s; s >>= 1) se += __shfl_xor(se, s);

  if (lane == 0) {
    const int cls = (int)tg[0];
    float val = mx + logf(se) - Lp[cls];
    const float d0 = Lp[400] - tg[1], d1 = Lp[401] - tg[2];
    val += 0.5f * (d0 * d0 + d1 * d1);
    const float s2 = softplus_(Lp[402]) - tg[3]; val += s2 * s2;
    const float s3 = softplus_(Lp[403]) - tg[4]; val += s3 * s3;
    val += softplus_(Lp[404]) - Lp[404] * tg[5];
    val += softplus_(Lp[405]) - Lp[405] * tg[6];
    val += softplus_(Lp[406]) - Lp[406] * tg[7];
    partials[gw] = val * (1.0f / 1024.0f);
  }
}

__global__ void k_reduce_final(const float* __restrict__ partials, float* __restrict__ out) {
  __shared__ float s[256];
  float v = 0.f;
  for (int i = threadIdx.x; i < 12288; i += 256) v += partials[i];
  s[threadIdx.x] = v;
  __syncthreads();
  for (int st = 128; st; st >>= 1) {
    if (threadIdx.x < st) s[threadIdx.x] += s[threadIdx.x + st];
    __syncthreads();
  }
  if (threadIdx.x == 0) out[0] = s[0];
}

// ---------------- launcher ----------------

extern "C" void kernel_launch(void* const* d_in, const int* in_sizes, int n_in,
                              void* d_out, int out_size, void* d_ws, size_t ws_size,
                              hipStream_t stream) {
  const float* obs      = (const float*)d_in[0];
  const float* actions  = (const float*)d_in[1];
  const float* beliefs  = (const float*)d_in[2];
  const float* w_ih     = (const float*)d_in[3];
  const float* w_hh     = (const float*)d_in[4];
  const float* b_ih     = (const float*)d_in[5];
  const float* b_hh     = (const float*)d_in[6];
  const float* pre_w1   = (const float*)d_in[7];
  const float* pre_b1   = (const float*)d_in[8];
  const float* pre_w2   = (const float*)d_in[9];
  const float* pre_b2   = (const float*)d_in[10];
  const float* dec_w    = (const float*)d_in[11];
  const float* dec_b    = (const float*)d_in[12];
  const int*   idx_i    = (const int*)d_in[13];
  const int*   Kmat     = (const int*)d_in[14];
  float* outF = (float*)d_out;

  char* p = (char*)d_ws;
  auto carve = [&](size_t bytes) {
    char* q = p;
    p += (bytes + 255) & ~(size_t)255;
    return q;
  };
  u8*   Wh8     = (u8*)carve(3072u * 1024u);
  bf16* Wib     = (bf16*)carve(3072u * 64u * 2u);
  bf16* actb    = (bf16*)carve(128u * 256u * 64u * 2u);
  bf16* preW1b  = (bf16*)carve(64u * 1024u * 2u);
  bf16* preW2b  = (bf16*)carve(1024u * 64u * 2u);
  bf16* decWb   = (bf16*)carve(814u * 1024u * 2u);
  u8*   hbuf    = (u8*)carve(31u * 1572864u);
  bf16* states  = (bf16*)carve(6144u * 1024u * 2u);
  bf16* h1      = (bf16*)carve(6144u * 64u * 2u);
  bf16* xbuf    = (bf16*)carve(6144u * 1024u * 2u);
  float* logits = (float*)carve((size_t)6144u * 814u * 4u);
  float* partials = (float*)carve(12288u * 4u);
  int*  done    = (int*)carve(480u * 4u);

  hipMemsetAsync(done, 0, 480u * sizeof(int), stream);
  // prewarm h step-buffers: full-line zero writes -> later partial WT stores hit
  // L3-resident lines (kills R13's 45MB of HBM write-allocate fetches)
  hipMemsetAsync(hbuf, 0, 31u * 1572864u, stream);

  k_prep<<<2048, 256, 0, stream>>>(w_hh, w_ih, actions, pre_w1, pre_w2, dec_w,
                                   beliefs, idx_i, Wh8, Wib, actb, preW1b, preW2b,
                                   decWb, hbuf);

  {
    void* args[] = {(void*)&hbuf, (void*)&Wh8, (void*)&Wib, (void*)&actb,
                    (void*)&b_ih, (void*)&b_hh, (void*)&idx_i, (void*)&Kmat,
                    (void*)&states, (void*)&done};
    hipLaunchCooperativeKernel((const void*)k_gru_all, dim3(512), dim3(256), args, 0, stream);
  }

  k_gemm_epi<0, 0><<<dim3(96, 1), 256, 0, stream>>>(states, preW1b, 1024, 64, 64,
                                                    pre_b1, nullptr, nullptr, h1);
  k_gemm_epi<1, 1><<<1536, 256, 0, stream>>>(h1, preW2b, 64, 1024, 1024,
                                             pre_b2, states, nullptr, xbuf);
  k_gemm_epi<2, 1><<<1248, 256, 0, stream>>>(xbuf, decWb, 1024, 814, 814,
                                             dec_b, nullptr, logits, nullptr);

  k_loss_wave<<<3072, 256, 0, stream>>>(logits, obs, idx_i, Kmat, partials);
  k_reduce_final<<<1, 256, 0, stream>>>(partials, outF);
}

// Round 17
// 763.615 us; speedup vs baseline: 1.5289x; 1.5289x over previous
//
#include <hip/hip_runtime.h>
#include <hip/hip_bf16.h>
#include <hip/hip_fp8.h>

typedef __bf16 bf16;
typedef unsigned char u8;
typedef __attribute__((ext_vector_type(4))) __bf16 bf16x4;
typedef __attribute__((ext_vector_type(8))) __bf16 bf16x8;
typedef __attribute__((ext_vector_type(4))) float f32x4;

static __device__ __forceinline__ f32x4 MFMA16(bf16x8 a, bf16x8 b, f32x4 c) {
  return __builtin_amdgcn_mfma_f32_16x16x32_bf16(a, b, c, 0, 0, 0);
}
static __device__ __forceinline__ f32x4 MFMA8(long a, long b, f32x4 c) {
  return __builtin_amdgcn_mfma_f32_16x16x32_fp8_fp8(a, b, c, 0, 0, 0);
}

__device__ __forceinline__ float sigm(float x) { return 1.0f / (1.0f + __expf(-x)); }
__device__ __forceinline__ float softplus_(float x) {
  return fmaxf(x, 0.0f) + log1pf(__expf(-fabsf(x)));
}
__device__ __forceinline__ u8 to_fp8(float x) {
  __hip_fp8_e4m3 v(x);
  return (u8)v.__x;
}
__device__ __forceinline__ float from_fp8(u8 b) {
  __hip_fp8_e4m3 v;
  v.__x = b;
  return (float)v;
}

__device__ __forceinline__ void gl16(const void* g, char* l) {
  __builtin_amdgcn_global_load_lds(
      (const __attribute__((address_space(1))) char*)g,
      (__attribute__((address_space(3))) char*)l, 16, 0, 0);
}

// ---------------- fused prep: conversions (bf16 + fp8) + h0(fp8) into hbuf[0] ----------------
__global__ void k_prep(const float* __restrict__ whh, const float* __restrict__ wih,
                       const float* __restrict__ act, const float* __restrict__ w1,
                       const float* __restrict__ w2, const float* __restrict__ dw,
                       const float* __restrict__ beliefs, const int* __restrict__ idx_i,
                       u8* __restrict__ Wh8, bf16* __restrict__ Wib,
                       bf16* __restrict__ actb, bf16* __restrict__ w1b,
                       bf16* __restrict__ w2b, bf16* __restrict__ dwb,
                       u8* __restrict__ hbuf) {
  for (int q = blockIdx.x * blockDim.x + threadIdx.x; q < 1994240;
       q += gridDim.x * blockDim.x) {
    if (q < 814592) {
      const float* src;
      bf16* dst;
      int off;
      if (q < 49152)       { src = wih; dst = Wib;  off = q; }
      else if (q < 573440) { src = act; dst = actb; off = q - 49152; }
      else if (q < 589824) { src = w1;  dst = w1b;  off = q - 573440; }
      else if (q < 606208) { src = w2;  dst = w2b;  off = q - 589824; }
      else                 { src = dw;  dst = dwb;  off = q - 606208; }
      float4 v = *(const float4*)&src[(size_t)off << 2];
      bf16x4 o = {(bf16)v.x, (bf16)v.y, (bf16)v.z, (bf16)v.w};
      *(bf16x4*)&dst[(size_t)off << 2] = o;
    } else if (q < 1207808) {
      const int e = (q - 814592) << 2;          // byte offset in h (1B/elem)
      const int n = e >> 18, rest = e & 262143;
      float4 v = *(const float4*)&beliefs[((size_t)idx_i[n] << 18) + rest];
      unsigned w = (unsigned)to_fp8(v.x) | ((unsigned)to_fp8(v.y) << 8) |
                   ((unsigned)to_fp8(v.z) << 16) | ((unsigned)to_fp8(v.w) << 24);
      const int par = (e >> 10) & 1;            // row parity (parity half-swap)
      *(unsigned*)&hbuf[e ^ (par << 3)] = w;
    } else {
      const int off = q - 1207808;
      float4 v = *(const float4*)&whh[(size_t)off << 2];
      unsigned w = (unsigned)to_fp8(v.x) | ((unsigned)to_fp8(v.y) << 8) |
                   ((unsigned)to_fp8(v.z) << 16) | ((unsigned)to_fp8(v.w) << 24);
      const int bo = off << 2;
      const int par = (bo >> 10) & 1;
      *(unsigned*)&Wh8[bo ^ (par << 3)] = w;
    }
  }
}

// ---------------- persistent GRU v4: XCD-CLOSED producer-consumer ----------------
// Each XCD owns a fixed 192-row slab for ALL 30 steps; its 64 blocks (2 mtl x 32 jt)
// tile all 1024 j internally. h for the slab is produced AND consumed inside one
// L2 -> plain write-back stores; consumers hit dirty L2 lines; fresh per-step
// buffer addresses make L1 staleness impossible. Wh8 (3MB) + slab h (192KB) + act
// L2-resident, fetched from L3 ONCE (vs 30x in R13/R16). Flags count 32 same-XCD
// producers (tight skew, short latency). Protocol otherwise validated in R13/R16.
__global__ __launch_bounds__(256, 2) void k_gru_all(
    u8* __restrict__ hbuf,
    const u8* __restrict__ Wh8, const bf16* __restrict__ Wib,
    const bf16* __restrict__ actb,
    const float* __restrict__ b_ih, const float* __restrict__ b_hh,
    const int* __restrict__ idx_i, const int* __restrict__ Kmat,
    bf16* __restrict__ states, int* __restrict__ done) {
  const int pid = blockIdx.x;
  const int xcd = pid & 7;            // XCD = row-slab owner
  const int mtl = (pid >> 3) & 1;     // half-slab (96 rows)
  const int jtl = pid >> 4;           // 0..31 j-tile within XCD
  const int m0 = xcd * 192 + mtl * 96;
  const int j0 = jtl * 32;
  const int mtIdx = xcd * 2 + mtl;

  int mk;
  {
    const int nlo = m0 >> 8, nhi = (m0 + 95) >> 8;
    mk = max(max(Kmat[nlo * 4 + 0], Kmat[nlo * 4 + 1]),
             max(Kmat[nlo * 4 + 2], Kmat[nlo * 4 + 3]));
    if (nhi != nlo)
      mk = max(mk, max(max(Kmat[nhi * 4 + 0], Kmat[nhi * 4 + 1]),
                       max(Kmat[nhi * 4 + 2], Kmat[nhi * 4 + 3])));
  }

  const int tid = threadIdx.x, wave = tid >> 6, lane = tid & 63;
  const int l15 = lane & 15;
  const int kgrp = lane >> 4;
  const int wm = wave >> 1;
  const int wj = wave & 1;
  const int jlane = j0 + wj * 16 + l15;

  __shared__ alignas(16) char As[3 * 12288];
  __shared__ alignas(16) char Bs[3 * 12288];
  __shared__ alignas(16) u8 HpL[96 * 40];      // persistent own h-tile (logical order)

  const int srow = lane >> 3;
  int a8off[3], b8off[3], aibase[3], bioff[3];
#pragma unroll
  for (int i = 0; i < 3; ++i) {
    const int r = wave * 24 + i * 8 + srow;
    const int grow = m0 + r;
    a8off[i] = grow * 1024 + ((((lane & 7) ^ ((r >> 1) & 7)) << 4));
    const int wr = (r >> 5) * 1024 + j0 + (r & 31);
    b8off[i] = wr * 1024 + ((((lane & 7) ^ ((r >> 1) & 7)) << 4));
    const int scol = (((lane & 7) ^ srow) << 3);
    const int np = grow >> 8;
    aibase[i] = (idx_i[np] * 256 + (grow & 255)) * 64 + scol;
    bioff[i] = wr * 64 + scol;
  }

  const float br = b_ih[jlane] + b_hh[jlane];
  const float bz = b_ih[1024 + jlane] + b_hh[1024 + jlane];
  const float bin = b_ih[2048 + jlane];
  const float bhn = b_hh[2048 + jlane];

  const int keyA = ((wm * 48 + l15) >> 1) & 7;
  const int keyB = ((wj * 16 + l15) >> 1) & 7;
  const int pa = (l15 & 1) << 3;

  // ---- hp init from hbuf[0] into persistent LDS ----
  {
    unsigned hv[3];
#pragma unroll
    for (int it2 = 0; it2 < 3; ++it2) {
      const int u = it2 * 256 + tid;
      const int row = u >> 3, c = u & 7;
      const int cs = c ^ ((row & 1) << 1);
      hv[it2] = *(const unsigned*)(hbuf + (size_t)(m0 + row) * 1024 + j0 + cs * 4);
    }
    asm volatile("s_waitcnt vmcnt(0)" ::: "memory");
#pragma unroll
    for (int it2 = 0; it2 < 3; ++it2) {
      const int u = it2 * 256 + tid;
      const int row = u >> 3, c = u & 7;
      *(unsigned*)&HpL[row * 40 + c * 4] = hv[it2];
    }
  }
  __syncthreads();

  f32x4 accR[3], accZ[3], accNh[3], accNi[3];
  const f32x4 zero = {0.f, 0.f, 0.f, 0.f};

  for (int s = 0; s <= mk; ++s) {
    const u8* hs = hbuf + (size_t)s * 1572864u;
    u8* hn = hbuf + (size_t)(s + 1) * 1572864u;

    auto stageB = [&](int buf, int slot) {
      char* bd = Bs + buf * 12288 + (wave * 24) * 128;
      if (slot < 8) {
#pragma unroll
        for (int i = 0; i < 3; ++i) gl16(Wh8 + b8off[i] + slot * 128, bd + i * 1024);
      } else {
#pragma unroll
        for (int i = 0; i < 3; ++i) gl16(Wib + bioff[i], bd + i * 1024);
      }
    };
    auto stageA = [&](int buf, int slot) {
      char* ad = As + buf * 12288 + (wave * 24) * 128;
      if (slot < 8) {
#pragma unroll
        for (int i = 0; i < 3; ++i) gl16(hs + a8off[i] + slot * 128, ad + i * 1024);
      } else {
#pragma unroll
        for (int i = 0; i < 3; ++i) gl16(actb + aibase[i] + s * 16384, ad + i * 1024);
      }
    };

    // overlap flag-wait with B-panel staging (B independent of h)
    stageB(0, 0);
    stageB(1, 1);
    if (s > 0) {
      if (tid == 0) {
        int guard = 0;
        while (__hip_atomic_load(&done[(s - 1) * 16 + mtIdx], __ATOMIC_RELAXED,
                                 __HIP_MEMORY_SCOPE_AGENT) < 32) {
          __builtin_amdgcn_s_sleep(1);
          if (++guard > (1 << 22)) break;   // fail-fast, never hang
        }
      }
      __syncthreads();
    }
    stageA(0, 0);
    stageA(1, 1);

#pragma unroll
    for (int f = 0; f < 3; ++f) { accR[f] = zero; accZ[f] = zero; accNh[f] = zero; accNi[f] = zero; }

    auto computeF8 = [&](int buf) {
      const char* ab = As + buf * 12288;
      const char* bb = Bs + buf * 12288;
      const int ra = wm * 48 + l15;
      const int rb = wj * 16 + l15;
#pragma unroll
      for (int kkI = 0; kkI < 4; ++kkI) {
        const int hi = kkI * 2 + (kgrp >> 1);
        const int lo = (kgrp & 1) << 3;
        const int offA = ((((hi ^ keyA) << 4) | lo) ^ pa);
        const int offB = ((((hi ^ keyB) << 4) | lo) ^ pa);
        long a0 = *(const long*)(ab + ra * 128 + offA);
        long a1 = *(const long*)(ab + (ra + 16) * 128 + offA);
        long a2 = *(const long*)(ab + (ra + 32) * 128 + offA);
        long b0 = *(const long*)(bb + rb * 128 + offB);
        long b1 = *(const long*)(bb + (rb + 32) * 128 + offB);
        long b2 = *(const long*)(bb + (rb + 64) * 128 + offB);
        accR[0] = MFMA8(a0, b0, accR[0]);
        accR[1] = MFMA8(a1, b0, accR[1]);
        accR[2] = MFMA8(a2, b0, accR[2]);
        accZ[0] = MFMA8(a0, b1, accZ[0]);
        accZ[1] = MFMA8(a1, b1, accZ[1]);
        accZ[2] = MFMA8(a2, b1, accZ[2]);
        accNh[0] = MFMA8(a0, b2, accNh[0]);
        accNh[1] = MFMA8(a1, b2, accNh[1]);
        accNh[2] = MFMA8(a2, b2, accNh[2]);
      }
    };
    auto computeGi = [&]() {
      const char* ab = As + 2 * 12288;
      const char* bb = Bs + 2 * 12288;
#pragma unroll
      for (int kkI = 0; kkI < 2; ++kkI) {
        const int kbyte = (((kkI << 5) + (kgrp << 3)) << 1) ^ ((l15 & 7) << 4);
        bf16x8 a0 = *(const bf16x8*)(ab + (wm * 48 + l15) * 128 + kbyte);
        bf16x8 a1 = *(const bf16x8*)(ab + (wm * 48 + 16 + l15) * 128 + kbyte);
        bf16x8 a2 = *(const bf16x8*)(ab + (wm * 48 + 32 + l15) * 128 + kbyte);
        bf16x8 b_r = *(const bf16x8*)(bb + (wj * 16 + l15) * 128 + kbyte);
        bf16x8 b_z = *(const bf16x8*)(bb + (32 + wj * 16 + l15) * 128 + kbyte);
        bf16x8 b_n = *(const bf16x8*)(bb + (64 + wj * 16 + l15) * 128 + kbyte);
        accR[0] = MFMA16(a0, b_r, accR[0]);
        accR[1] = MFMA16(a1, b_r, accR[1]);
        accR[2] = MFMA16(a2, b_r, accR[2]);
        accZ[0] = MFMA16(a0, b_z, accZ[0]);
        accZ[1] = MFMA16(a1, b_z, accZ[1]);
        accZ[2] = MFMA16(a2, b_z, accZ[2]);
        accNi[0] = MFMA16(a0, b_n, accNi[0]);
        accNi[1] = MFMA16(a1, b_n, accNi[1]);
        accNi[2] = MFMA16(a2, b_n, accNi[2]);
      }
    };

#pragma unroll
    for (int t = 0; t < 9; ++t) {
      if (t < 7) { stageA((t + 2) % 3, t + 2); stageB((t + 2) % 3, t + 2); }
      if (t == 0)      asm volatile("s_waitcnt vmcnt(9)" ::: "memory");
      else if (t <= 6) asm volatile("s_waitcnt vmcnt(12)" ::: "memory");
      else if (t == 7) asm volatile("s_waitcnt vmcnt(6)" ::: "memory");
      else             asm volatile("s_waitcnt vmcnt(0)" ::: "memory");
      __builtin_amdgcn_s_barrier();
      if (t == 8) computeGi();
      else        computeF8(t % 3);
      __builtin_amdgcn_sched_barrier(0);
      __builtin_amdgcn_s_barrier();
    }

    // ---- epilogue: gates from persistent LDS hp (in-place update) ----
    bf16* Hn = (bf16*)Bs;   // bf16 transpose tile for states (Bs buf0 dead)
#pragma unroll
    for (int mf = 0; mf < 3; ++mf) {
#pragma unroll
      for (int ii = 0; ii < 4; ++ii) {
        const int ml = wm * 48 + mf * 16 + kgrp * 4 + ii;
        const int jl = wj * 16 + l15;
        float hp = from_fp8(HpL[ml * 40 + jl]);
        float rg2 = sigm(accR[mf][ii] + br);
        float zg = sigm(accZ[mf][ii] + bz);
        float ng = tanhf(accNi[mf][ii] + bin + rg2 * (accNh[mf][ii] + bhn));
        float hnew = (1.0f - zg) * ng + zg * hp;
        HpL[ml * 40 + jl] = to_fp8(hnew);     // in-place: same thread owns (ml,jl)
        Hn[ml * 40 + jl] = (bf16)hnew;
      }
    }
    __syncthreads();

    // h out: plain write-back stores (same-XCD consumers hit dirty L2 lines)
#pragma unroll
    for (int it2 = 0; it2 < 3; ++it2) {
      const int u = it2 * 256 + tid;
      const int row = u >> 3, c = u & 7;
      const int cs = c ^ ((row & 1) << 1);
      *(unsigned*)(hn + (size_t)(m0 + row) * 1024 + j0 + cs * 4) =
          *(const unsigned*)&HpL[row * 40 + c * 4];
      const int m = m0 + row;
      const int n = m >> 8;
      const int b = m & 255;
#pragma unroll
      for (int g = 0; g < 4; ++g) {
        if (Kmat[n * 4 + g] == s) {
          uint2 v;
          v.x = *(const unsigned*)&Hn[row * 40 + c * 4];
          v.y = *(const unsigned*)&Hn[row * 40 + c * 4 + 2];
          *(uint2*)&states[((size_t)(n * 4 + g) * 256 + b) * 1024 + j0 + c * 4] = v;
        }
      }
    }

    asm volatile("s_waitcnt vmcnt(0)" ::: "memory");
    __syncthreads();
    if (tid == 0)
      __hip_atomic_fetch_add(&done[s * 16 + mtIdx], 1, __ATOMIC_RELAXED,
                             __HIP_MEMORY_SCOPE_AGENT);
  }
}

// ---------------- generic GEMM: C = A(M x K) @ W(N x K)^T, fused epilogues ----------------
template <int EPI, int SWZ>
__global__ __launch_bounds__(256) void k_gemm_epi(
    const bf16* __restrict__ A, const bf16* __restrict__ W, int K, int Nreal, int ld_out,
    const float* __restrict__ bias, const bf16* __restrict__ resid,
    float* __restrict__ outF, bf16* __restrict__ outB) {
  int mt, jt;
  if (SWZ) {
    const int lin = blockIdx.x;
    const int x = lin & 7, k = lin >> 3;
    mt = 12 * x + k % 12;
    jt = k / 12;
  } else {
    mt = blockIdx.x;
    jt = blockIdx.y;
  }
  const int m0 = mt * 64;
  const int j0 = jt * 64;
  const int tid = threadIdx.x, wave = tid >> 6, lane = tid & 63;
  __shared__ alignas(16) bf16 Al[64][72];
  __shared__ alignas(16) bf16 Wl[64][72];

  f32x4 acc[4];
  const f32x4 zero = {0.f, 0.f, 0.f, 0.f};
#pragma unroll
  for (int f = 0; f < 4; ++f) acc[f] = zero;

  const int r = tid >> 3, c8 = (tid & 7) << 3;
  const int arow = wave * 16 + (lane & 15);
  const int koff = (lane >> 4) << 3;

  for (int kb = 0; kb < K; kb += 64) {
    *(bf16x8*)&Al[r][c8]      = *(const bf16x8*)&A[(size_t)(m0 + r) * K + kb + c8];
    *(bf16x8*)&Al[r + 32][c8] = *(const bf16x8*)&A[(size_t)(m0 + r + 32) * K + kb + c8];
    int jr = j0 + r;      if (jr >= Nreal) jr = Nreal - 1;
    int jr2 = j0 + r + 32; if (jr2 >= Nreal) jr2 = Nreal - 1;
    *(bf16x8*)&Wl[r][c8]      = *(const bf16x8*)&W[(size_t)jr * K + kb + c8];
    *(bf16x8*)&Wl[r + 32][c8] = *(const bf16x8*)&W[(size_t)jr2 * K + kb + c8];
    __syncthreads();
#pragma unroll
    for (int kk = 0; kk < 64; kk += 32) {
      bf16x8 av = *(const bf16x8*)&Al[arow][kk + koff];
#pragma unroll
      for (int nf = 0; nf < 4; ++nf) {
        acc[nf] = MFMA16(av, *(const bf16x8*)&Wl[nf * 16 + (lane & 15)][kk + koff], acc[nf]);
      }
    }
    __syncthreads();
  }

#pragma unroll
  for (int nf = 0; nf < 4; ++nf) {
    int j = j0 + nf * 16 + (lane & 15);
    float bj = (j < Nreal) ? bias[j] : 0.f;
#pragma unroll
    for (int i = 0; i < 4; ++i) {
      int m = m0 + wave * 16 + ((lane >> 4) << 2) + i;
      float v = acc[nf][i] + bj;
      if (EPI == 0) {
        outB[(size_t)m * ld_out + j] = (bf16)fmaxf(v, 0.f);
      } else if (EPI == 1) {
        v = fmaxf(v, 0.f) + (float)resid[(size_t)m * ld_out + j];
        outB[(size_t)m * ld_out + j] = (bf16)v;
      } else {
        if (j < Nreal) outF[(size_t)m * ld_out + j] = v;
      }
    }
  }
}

// ---------------- loss: one wave per (row, player-head) ----------------
__global__ __launch_bounds__(256) void k_loss_wave(
    const float* __restrict__ logits, const float* __restrict__ obs,
    const int* __restrict__ idx_i, const int* __restrict__ Kmat,
    float* __restrict__ partials) {
  const int gw = blockIdx.x * 4 + (threadIdx.x >> 6);
  const int lane = threadIdx.x & 63;
  const int row = gw >> 1, p = gw & 1;
  const int n = row >> 10, g = (row >> 8) & 3, b = row & 255;
  const int i = idx_i[n], k = Kmat[n * 4 + g];
  const float* Lp = logits + (size_t)row * 814 + p * 407;
  const float* tg = obs + ((size_t)(k + i + 1) * 256 + b) * 16 + p * 8;

  float v[7];
#pragma unroll
  for (int it = 0; it < 7; ++it) {
    const int c = lane + it * 64;
    v[it] = (c < 400) ? Lp[c] : -1e30f;
  }
  float mx = fmaxf(fmaxf(fmaxf(v[0], v[1]), fmaxf(v[2], v[3])),
                   fmaxf(fmaxf(v[4], v[5]), v[6]));
#pragma unroll
  for (int s = 32; s; s >>= 1) mx = fmaxf(mx, __shfl_xor(mx, s));
  float se = 0.f;
#pragma unroll
  for (int it = 0; it < 7; ++it) {
    const int c = lane + it * 64;
    se += (c < 400) ? __expf(v[it] - mx) : 0.f;
  }
#pragma unroll
  for (int s = 32; s; s >>= 1) se += __shfl_xor(se, s);

  if (lane == 0) {
    const int cls = (int)tg[0];
    float val = mx + logf(se) - Lp[cls];
    const float d0 = Lp[400] - tg[1], d1 = Lp[401] - tg[2];
    val += 0.5f * (d0 * d0 + d1 * d1);
    const float s2 = softplus_(Lp[402]) - tg[3]; val += s2 * s2;
    const float s3 = softplus_(Lp[403]) - tg[4]; val += s3 * s3;
    val += softplus_(Lp[404]) - Lp[404] * tg[5];
    val += softplus_(Lp[405]) - Lp[405] * tg[6];
    val += softplus_(Lp[406]) - Lp[406] * tg[7];
    partials[gw] = val * (1.0f / 1024.0f);
  }
}

__global__ void k_reduce_final(const float* __restrict__ partials, float* __restrict__ out) {
  __shared__ float s[256];
  float v = 0.f;
  for (int i = threadIdx.x; i < 12288; i += 256) v += partials[i];
  s[threadIdx.x] = v;
  __syncthreads();
  for (int st = 128; st; st >>= 1) {
    if (threadIdx.x < st) s[threadIdx.x] += s[threadIdx.x + st];
    __syncthreads();
  }
  if (threadIdx.x == 0) out[0] = s[0];
}

// ---------------- launcher ----------------

extern "C" void kernel_launch(void* const* d_in, const int* in_sizes, int n_in,
                              void* d_out, int out_size, void* d_ws, size_t ws_size,
                              hipStream_t stream) {
  const float* obs      = (const float*)d_in[0];
  const float* actions  = (const float*)d_in[1];
  const float* beliefs  = (const float*)d_in[2];
  const float* w_ih     = (const float*)d_in[3];
  const float* w_hh     = (const float*)d_in[4];
  const float* b_ih     = (const float*)d_in[5];
  const float* b_hh     = (const float*)d_in[6];
  const float* pre_w1   = (const float*)d_in[7];
  const float* pre_b1   = (const float*)d_in[8];
  const float* pre_w2   = (const float*)d_in[9];
  const float* pre_b2   = (const float*)d_in[10];
  const float* dec_w    = (const float*)d_in[11];
  const float* dec_b    = (const float*)d_in[12];
  const int*   idx_i    = (const int*)d_in[13];
  const int*   Kmat     = (const int*)d_in[14];
  float* outF = (float*)d_out;

  char* p = (char*)d_ws;
  auto carve = [&](size_t bytes) {
    char* q = p;
    p += (bytes + 255) & ~(size_t)255;
    return q;
  };
  u8*   Wh8     = (u8*)carve(3072u * 1024u);
  bf16* Wib     = (bf16*)carve(3072u * 64u * 2u);
  bf16* actb    = (bf16*)carve(128u * 256u * 64u * 2u);
  bf16* preW1b  = (bf16*)carve(64u * 1024u * 2u);
  bf16* preW2b  = (bf16*)carve(1024u * 64u * 2u);
  bf16* decWb   = (bf16*)carve(814u * 1024u * 2u);
  u8*   hbuf    = (u8*)carve(31u * 1572864u);
  bf16* states  = (bf16*)carve(6144u * 1024u * 2u);
  bf16* h1      = (bf16*)carve(6144u * 64u * 2u);
  bf16* xbuf    = (bf16*)carve(6144u * 1024u * 2u);
  float* logits = (float*)carve((size_t)6144u * 814u * 4u);
  float* partials = (float*)carve(12288u * 4u);
  int*  done    = (int*)carve(480u * 4u);

  hipMemsetAsync(done, 0, 480u * sizeof(int), stream);
  hipMemsetAsync(hbuf, 0, 31u * 1572864u, stream);   // prewarm: no HBM write-allocate

  k_prep<<<2048, 256, 0, stream>>>(w_hh, w_ih, actions, pre_w1, pre_w2, dec_w,
                                   beliefs, idx_i, Wh8, Wib, actb, preW1b, preW2b,
                                   decWb, hbuf);

  {
    void* args[] = {(void*)&hbuf, (void*)&Wh8, (void*)&Wib, (void*)&actb,
                    (void*)&b_ih, (void*)&b_hh, (void*)&idx_i, (void*)&Kmat,
                    (void*)&states, (void*)&done};
    hipLaunchCooperativeKernel((const void*)k_gru_all, dim3(512), dim3(256), args, 0, stream);
  }

  k_gemm_epi<0, 0><<<dim3(96, 1), 256, 0, stream>>>(states, preW1b, 1024, 64, 64,
                                                    pre_b1, nullptr, nullptr, h1);
  k_gemm_epi<1, 1><<<1536, 256, 0, stream>>>(h1, preW2b, 64, 1024, 1024,
                                             pre_b2, states, nullptr, xbuf);
  k_gemm_epi<2, 1><<<1248, 256, 0, stream>>>(xbuf, decWb, 1024, 814, 814,
                                             dec_b, nullptr, logits, nullptr);

  k_loss_wave<<<3072, 256, 0, stream>>>(logits, obs, idx_i, Kmat, partials);
  k_reduce_final<<<1, 256, 0, stream>>>(partials, outF);
}

// Round 18
// 535.335 us; speedup vs baseline: 2.1809x; 1.4264x over previous
//
#include <hip/hip_runtime.h>
#include <hip/hip_bf16.h>
#include <hip/hip_fp8.h>

typedef __bf16 bf16;
typedef unsigned char u8;
typedef __attribute__((ext_vector_type(4))) __bf16 bf16x4;
typedef __attribute__((ext_vector_type(8))) __bf16 bf16x8;
typedef __attribute__((ext_vector_type(4))) float f32x4;

static __device__ __forceinline__ f32x4 MFMA16(bf16x8 a, bf16x8 b, f32x4 c) {
  return __builtin_amdgcn_mfma_f32_16x16x32_bf16(a, b, c, 0, 0, 0);
}
static __device__ __forceinline__ f32x4 MFMA8(long a, long b, f32x4 c) {
  return __builtin_amdgcn_mfma_f32_16x16x32_fp8_fp8(a, b, c, 0, 0, 0);
}

__device__ __forceinline__ float sigm(float x) { return 1.0f / (1.0f + __expf(-x)); }
__device__ __forceinline__ float softplus_(float x) {
  return fmaxf(x, 0.0f) + log1pf(__expf(-fabsf(x)));
}
__device__ __forceinline__ u8 to_fp8(float x) {
  __hip_fp8_e4m3 v(x);
  return (u8)v.__x;
}
__device__ __forceinline__ float from_fp8(u8 b) {
  __hip_fp8_e4m3 v;
  v.__x = b;
  return (float)v;
}

__device__ __forceinline__ void gl16(const void* g, char* l) {
  __builtin_amdgcn_global_load_lds(
      (const __attribute__((address_space(1))) char*)g,
      (__attribute__((address_space(3))) char*)l, 16, 0, 0);
}

// ---------------- fused prep: conversions (bf16 + fp8) + h0(fp8) init ----------------
// fp8 arrays (Wh8, hA8) stored with 8B halves of each 16B block swapped on odd
// rows (parity half-swap -> conflict-free ds_read_b64; R13 diagnosis, R14 fix).
__global__ void k_prep(const float* __restrict__ whh, const float* __restrict__ wih,
                       const float* __restrict__ act, const float* __restrict__ w1,
                       const float* __restrict__ w2, const float* __restrict__ dw,
                       const float* __restrict__ beliefs, const int* __restrict__ idx_i,
                       u8* __restrict__ Wh8, bf16* __restrict__ Wib,
                       bf16* __restrict__ actb, bf16* __restrict__ w1b,
                       bf16* __restrict__ w2b, bf16* __restrict__ dwb,
                       u8* __restrict__ hA8) {
  for (int q = blockIdx.x * blockDim.x + threadIdx.x; q < 1994240;
       q += gridDim.x * blockDim.x) {
    if (q < 814592) {
      const float* src;
      bf16* dst;
      int off;
      if (q < 49152)       { src = wih; dst = Wib;  off = q; }
      else if (q < 573440) { src = act; dst = actb; off = q - 49152; }
      else if (q < 589824) { src = w1;  dst = w1b;  off = q - 573440; }
      else if (q < 606208) { src = w2;  dst = w2b;  off = q - 589824; }
      else                 { src = dw;  dst = dwb;  off = q - 606208; }
      float4 v = *(const float4*)&src[(size_t)off << 2];
      bf16x4 o = {(bf16)v.x, (bf16)v.y, (bf16)v.z, (bf16)v.w};
      *(bf16x4*)&dst[(size_t)off << 2] = o;
    } else if (q < 1207808) {
      const int e = (q - 814592) << 2;          // byte offset (1B/elem)
      const int n = e >> 18, rest = e & 262143;
      float4 v = *(const float4*)&beliefs[((size_t)idx_i[n] << 18) + rest];
      unsigned w = (unsigned)to_fp8(v.x) | ((unsigned)to_fp8(v.y) << 8) |
                   ((unsigned)to_fp8(v.z) << 16) | ((unsigned)to_fp8(v.w) << 24);
      const int par = (e >> 10) & 1;            // row (m) parity
      *(unsigned*)&hA8[e ^ (par << 3)] = w;
    } else {
      const int off = q - 1207808;
      float4 v = *(const float4*)&whh[(size_t)off << 2];
      unsigned w = (unsigned)to_fp8(v.x) | ((unsigned)to_fp8(v.y) << 8) |
                   ((unsigned)to_fp8(v.z) << 16) | ((unsigned)to_fp8(v.w) << 24);
      const int bo = off << 2;
      const int par = (bo >> 10) & 1;
      *(unsigned*)&Wh8[bo ^ (par << 3)] = w;
    }
  }
}

// ---------------- GRU step v12: fp8-only h state (R15) + states-write FIX ----------------
// Best-measured config (R15, 535us) with the latent states epilogue defect repaired
// (was c*8 element indexing -> half-row writes + races; now R14's verified c*4 uint2).
__global__ __launch_bounds__(256, 2) void k_gru_step(
    const u8* __restrict__ hin8, u8* __restrict__ hout8,
    const u8* __restrict__ Wh8, const bf16* __restrict__ Wib,
    const bf16* __restrict__ actb,
    const float* __restrict__ b_ih, const float* __restrict__ b_hh,
    const int* __restrict__ idx_i, const int* __restrict__ Kmat,
    bf16* __restrict__ states, int step) {
  const int pid = blockIdx.x;
  const int xcd = pid & 7;
  const int rg = xcd >> 2;
  const int cgp = xcd & 3;
  const int q = pid >> 3;
  const int mtl = q & 7;
  const int jtl = q >> 3;
  const int m0 = rg * 768 + mtl * 96;
  const int j0 = (cgp * 8 + jtl) * 32;

  {
    const int nlo = m0 >> 8, nhi = (m0 + 95) >> 8;
    int mk = max(max(Kmat[nlo * 4 + 0], Kmat[nlo * 4 + 1]),
                 max(Kmat[nlo * 4 + 2], Kmat[nlo * 4 + 3]));
    if (nhi != nlo)
      mk = max(mk, max(max(Kmat[nhi * 4 + 0], Kmat[nhi * 4 + 1]),
                       max(Kmat[nhi * 4 + 2], Kmat[nhi * 4 + 3])));
    if (step > mk) return;
  }

  const int tid = threadIdx.x, wave = tid >> 6, lane = tid & 63;
  const int l15 = lane & 15;
  const int kgrp = lane >> 4;
  const int wm = wave >> 1;
  const int wj = wave & 1;
  const int jlane = j0 + wj * 16 + l15;

  __shared__ alignas(16) char As[3 * 12288];
  __shared__ alignas(16) char Bs[3 * 12288];

  const int srow = lane >> 3;
  int a8off[3], b8off[3], aioff[3], bioff[3];
#pragma unroll
  for (int i = 0; i < 3; ++i) {
    const int r = wave * 24 + i * 8 + srow;
    const int grow = m0 + r;
    a8off[i] = grow * 1024 + ((((lane & 7) ^ ((r >> 1) & 7)) << 4));
    const int wr = (r >> 5) * 1024 + j0 + (r & 31);
    b8off[i] = wr * 1024 + ((((lane & 7) ^ ((r >> 1) & 7)) << 4));
    const int scol = (((lane & 7) ^ srow) << 3);
    const int np = grow >> 8;
    aioff[i] = ((idx_i[np] + step) * 256 + (grow & 255)) * 64 + scol;
    bioff[i] = wr * 64 + scol;
  }

  auto stage = [&](int buf, int slot) {
    char* ad = As + buf * 12288 + (wave * 24) * 128;
    char* bd = Bs + buf * 12288 + (wave * 24) * 128;
    if (slot < 8) {
#pragma unroll
      for (int i = 0; i < 3; ++i) {
        gl16(hin8 + a8off[i] + slot * 128, ad + i * 1024);
        gl16(Wh8 + b8off[i] + slot * 128, bd + i * 1024);
      }
    } else {
#pragma unroll
      for (int i = 0; i < 3; ++i) {
        gl16(actb + aioff[i], ad + i * 1024);
        gl16(Wib + bioff[i], bd + i * 1024);
      }
    }
  };

  f32x4 accR[3], accZ[3], accNh[3], accNi[3];
  const f32x4 zero = {0.f, 0.f, 0.f, 0.f};
#pragma unroll
  for (int f = 0; f < 3; ++f) { accR[f] = zero; accZ[f] = zero; accNh[f] = zero; accNi[f] = zero; }

  const float br = b_ih[jlane] + b_hh[jlane];
  const float bz = b_ih[1024 + jlane] + b_hh[1024 + jlane];
  const float bin = b_ih[2048 + jlane];
  const float bhn = b_hh[2048 + jlane];

  const int keyA = ((wm * 48 + l15) >> 1) & 7;
  const int keyB = ((wj * 16 + l15) >> 1) & 7;
  const int pa = (l15 & 1) << 3;   // parity half-swap bit

  auto computeF8 = [&](int buf) {
    const char* ab = As + buf * 12288;
    const char* bb = Bs + buf * 12288;
    const int ra = wm * 48 + l15;
    const int rb = wj * 16 + l15;
#pragma unroll
    for (int kkI = 0; kkI < 4; ++kkI) {
      const int hi = kkI * 2 + (kgrp >> 1);
      const int lo = (kgrp & 1) << 3;
      const int offA = ((((hi ^ keyA) << 4) | lo) ^ pa);
      const int offB = ((((hi ^ keyB) << 4) | lo) ^ pa);
      long a0 = *(const long*)(ab + ra * 128 + offA);
      long a1 = *(const long*)(ab + (ra + 16) * 128 + offA);
      long a2 = *(const long*)(ab + (ra + 32) * 128 + offA);
      long b0 = *(const long*)(bb + rb * 128 + offB);
      long b1 = *(const long*)(bb + (rb + 32) * 128 + offB);
      long b2 = *(const long*)(bb + (rb + 64) * 128 + offB);
      accR[0] = MFMA8(a0, b0, accR[0]);
      accR[1] = MFMA8(a1, b0, accR[1]);
      accR[2] = MFMA8(a2, b0, accR[2]);
      accZ[0] = MFMA8(a0, b1, accZ[0]);
      accZ[1] = MFMA8(a1, b1, accZ[1]);
      accZ[2] = MFMA8(a2, b1, accZ[2]);
      accNh[0] = MFMA8(a0, b2, accNh[0]);
      accNh[1] = MFMA8(a1, b2, accNh[1]);
      accNh[2] = MFMA8(a2, b2, accNh[2]);
    }
  };

  auto computeGi = [&]() {
    const char* ab = As + 2 * 12288;
    const char* bb = Bs + 2 * 12288;
#pragma unroll
    for (int kkI = 0; kkI < 2; ++kkI) {
      const int kbyte = (((kkI << 5) + (kgrp << 3)) << 1) ^ ((l15 & 7) << 4);
      bf16x8 a0 = *(const bf16x8*)(ab + (wm * 48 + l15) * 128 + kbyte);
      bf16x8 a1 = *(const bf16x8*)(ab + (wm * 48 + 16 + l15) * 128 + kbyte);
      bf16x8 a2 = *(const bf16x8*)(ab + (wm * 48 + 32 + l15) * 128 + kbyte);
      bf16x8 b_r = *(const bf16x8*)(bb + (wj * 16 + l15) * 128 + kbyte);
      bf16x8 b_z = *(const bf16x8*)(bb + (32 + wj * 16 + l15) * 128 + kbyte);
      bf16x8 b_n = *(const bf16x8*)(bb + (64 + wj * 16 + l15) * 128 + kbyte);
      accR[0] = MFMA16(a0, b_r, accR[0]);
      accR[1] = MFMA16(a1, b_r, accR[1]);
      accR[2] = MFMA16(a2, b_r, accR[2]);
      accZ[0] = MFMA16(a0, b_z, accZ[0]);
      accZ[1] = MFMA16(a1, b_z, accZ[1]);
      accZ[2] = MFMA16(a2, b_z, accZ[2]);
      accNi[0] = MFMA16(a0, b_n, accNi[0]);
      accNi[1] = MFMA16(a1, b_n, accNi[1]);
      accNi[2] = MFMA16(a2, b_n, accNi[2]);
    }
  };

  stage(0, 0);
  stage(1, 1);

  unsigned hp8reg[3];

#pragma unroll
  for (int t = 0; t < 9; ++t) {
    if (t < 7) stage((t + 2) % 3, t + 2);
    if (t == 6) {
      // hp prefetch from fp8 h (L2-hot), un-swizzling parity swap
#pragma unroll
      for (int it2 = 0; it2 < 3; ++it2) {
        const int u = it2 * 256 + tid;
        const int row = u >> 3, c = u & 7;
        const int cs = c ^ ((row & 1) << 1);
        hp8reg[it2] =
            *(const unsigned*)(hin8 + (size_t)(m0 + row) * 1024 + j0 + cs * 4);
      }
    }
    if (t <= 5)       asm volatile("s_waitcnt vmcnt(12)" ::: "memory");
    else if (t == 6)  asm volatile("s_waitcnt vmcnt(15)" ::: "memory");
    else if (t == 7)  asm volatile("s_waitcnt vmcnt(9)" ::: "memory");
    else              asm volatile("s_waitcnt vmcnt(3)" ::: "memory");
    __builtin_amdgcn_s_barrier();
    if (t == 8) computeGi();
    else        computeF8(t % 3);
    __builtin_amdgcn_sched_barrier(0);
    __builtin_amdgcn_s_barrier();
  }

  // ---- epilogue: LDS transpose; fp8 h out (+ bf16 states when sampled) ----
  asm volatile("s_waitcnt vmcnt(0)" ::: "memory");   // hp8reg landed
  u8* Hp8 = (u8*)As;               // stride 40 B
  bf16* Hn = (bf16*)Bs;            // stride 40 elems (80 B)
  u8* Hn8 = (u8*)(As + 12288);     // stride 40 B

#pragma unroll
  for (int it2 = 0; it2 < 3; ++it2) {
    const int u = it2 * 256 + tid;
    const int row = u >> 3, c = u & 7;
    *(unsigned*)&Hp8[row * 40 + c * 4] = hp8reg[it2];   // logical order
  }
  __syncthreads();

#pragma unroll
  for (int mf = 0; mf < 3; ++mf) {
#pragma unroll
    for (int ii = 0; ii < 4; ++ii) {
      const int ml = wm * 48 + mf * 16 + kgrp * 4 + ii;
      const int jl = wj * 16 + l15;
      float hp = from_fp8(Hp8[ml * 40 + jl]);
      float rg2 = sigm(accR[mf][ii] + br);
      float zg = sigm(accZ[mf][ii] + bz);
      float ng = tanhf(accNi[mf][ii] + bin + rg2 * (accNh[mf][ii] + bhn));
      float hnew = (1.0f - zg) * ng + zg * hp;
      Hn[ml * 40 + jl] = (bf16)hnew;
      Hn8[ml * 40 + jl] = to_fp8(hnew);
    }
  }
  __syncthreads();

  // fp8 h out (parity swizzle baked into global position) + FIXED states write:
  // per row, c=0..7 x uint2(4 bf16) at element c*4 covers all 32 cols exactly once.
#pragma unroll
  for (int it2 = 0; it2 < 3; ++it2) {
    const int u = it2 * 256 + tid;
    const int row = u >> 3, c = u & 7;
    const int cs = c ^ ((row & 1) << 1);
    *(unsigned*)&hout8[(size_t)(m0 + row) * 1024 + j0 + cs * 4] =
        *(const unsigned*)&Hn8[row * 40 + c * 4];
    const int m = m0 + row;
    const int n = m >> 8;
    const int b = m & 255;
    uint2 v = *(const uint2*)&Hn[row * 40 + c * 4];
#pragma unroll
    for (int g = 0; g < 4; ++g) {
      if (Kmat[n * 4 + g] == step)
        *(uint2*)&states[((size_t)(n * 4 + g) * 256 + b) * 1024 + j0 + c * 4] = v;
    }
  }
}

// ---------------- generic GEMM: C = A(M x K) @ W(N x K)^T, fused epilogues ----------------
template <int EPI, int SWZ>
__global__ __launch_bounds__(256) void k_gemm_epi(
    const bf16* __restrict__ A, const bf16* __restrict__ W, int K, int Nreal, int ld_out,
    const float* __restrict__ bias, const bf16* __restrict__ resid,
    float* __restrict__ outF, bf16* __restrict__ outB) {
  int mt, jt;
  if (SWZ) {
    const int lin = blockIdx.x;
    const int x = lin & 7, k = lin >> 3;
    mt = 12 * x + k % 12;
    jt = k / 12;
  } else {
    mt = blockIdx.x;
    jt = blockIdx.y;
  }
  const int m0 = mt * 64;
  const int j0 = jt * 64;
  const int tid = threadIdx.x, wave = tid >> 6, lane = tid & 63;
  __shared__ alignas(16) bf16 Al[64][72];
  __shared__ alignas(16) bf16 Wl[64][72];

  f32x4 acc[4];
  const f32x4 zero = {0.f, 0.f, 0.f, 0.f};
#pragma unroll
  for (int f = 0; f < 4; ++f) acc[f] = zero;

  const int r = tid >> 3, c8 = (tid & 7) << 3;
  const int arow = wave * 16 + (lane & 15);
  const int koff = (lane >> 4) << 3;

  for (int kb = 0; kb < K; kb += 64) {
    *(bf16x8*)&Al[r][c8]      = *(const bf16x8*)&A[(size_t)(m0 + r) * K + kb + c8];
    *(bf16x8*)&Al[r + 32][c8] = *(const bf16x8*)&A[(size_t)(m0 + r + 32) * K + kb + c8];
    int jr = j0 + r;      if (jr >= Nreal) jr = Nreal - 1;
    int jr2 = j0 + r + 32; if (jr2 >= Nreal) jr2 = Nreal - 1;
    *(bf16x8*)&Wl[r][c8]      = *(const bf16x8*)&W[(size_t)jr * K + kb + c8];
    *(bf16x8*)&Wl[r + 32][c8] = *(const bf16x8*)&W[(size_t)jr2 * K + kb + c8];
    __syncthreads();
#pragma unroll
    for (int kk = 0; kk < 64; kk += 32) {
      bf16x8 av = *(const bf16x8*)&Al[arow][kk + koff];
#pragma unroll
      for (int nf = 0; nf < 4; ++nf) {
        acc[nf] = MFMA16(av, *(const bf16x8*)&Wl[nf * 16 + (lane & 15)][kk + koff], acc[nf]);
      }
    }
    __syncthreads();
  }

#pragma unroll
  for (int nf = 0; nf < 4; ++nf) {
    int j = j0 + nf * 16 + (lane & 15);
    float bj = (j < Nreal) ? bias[j] : 0.f;
#pragma unroll
    for (int i = 0; i < 4; ++i) {
      int m = m0 + wave * 16 + ((lane >> 4) << 2) + i;
      float v = acc[nf][i] + bj;
      if (EPI == 0) {
        outB[(size_t)m * ld_out + j] = (bf16)fmaxf(v, 0.f);
      } else if (EPI == 1) {
        v = fmaxf(v, 0.f) + (float)resid[(size_t)m * ld_out + j];
        outB[(size_t)m * ld_out + j] = (bf16)v;
      } else {
        if (j < Nreal) outF[(size_t)m * ld_out + j] = v;
      }
    }
  }
}

// ---------------- loss: one wave per (row, player-head) ----------------
__global__ __launch_bounds__(256) void k_loss_wave(
    const float* __restrict__ logits, const float* __restrict__ obs,
    const int* __restrict__ idx_i, const int* __restrict__ Kmat,
    float* __restrict__ partials) {
  const int gw = blockIdx.x * 4 + (threadIdx.x >> 6);
  const int lane = threadIdx.x & 63;
  const int row = gw >> 1, p = gw & 1;
  const int n = row >> 10, g = (row >> 8) & 3, b = row & 255;
  const int i = idx_i[n], k = Kmat[n * 4 + g];
  const float* Lp = logits + (size_t)row * 814 + p * 407;
  const float* tg = obs + ((size_t)(k + i + 1) * 256 + b) * 16 + p * 8;

  float v[7];
#pragma unroll
  for (int it = 0; it < 7; ++it) {
    const int c = lane + it * 64;
    v[it] = (c < 400) ? Lp[c] : -1e30f;
  }
  float mx = fmaxf(fmaxf(fmaxf(v[0], v[1]), fmaxf(v[2], v[3])),
                   fmaxf(fmaxf(v[4], v[5]), v[6]));
#pragma unroll
  for (int s = 32; s; s >>= 1) mx = fmaxf(mx, __shfl_xor(mx, s));
  float se = 0.f;
#pragma unroll
  for (int it = 0; it < 7; ++it) {
    const int c = lane + it * 64;
    se += (c < 400) ? __expf(v[it] - mx) : 0.f;
  }
#pragma unroll
  for (int s = 32; s; s >>= 1) se += __shfl_xor(se, s);

  if (lane == 0) {
    const int cls = (int)tg[0];
    float val = mx + logf(se) - Lp[cls];
    const float d0 = Lp[400] - tg[1], d1 = Lp[401] - tg[2];
    val += 0.5f * (d0 * d0 + d1 * d1);
    const float s2 = softplus_(Lp[402]) - tg[3]; val += s2 * s2;
    const float s3 = softplus_(Lp[403]) - tg[4]; val += s3 * s3;
    val += softplus_(Lp[404]) - Lp[404] * tg[5];
    val += softplus_(Lp[405]) - Lp[405] * tg[6];
    val += softplus_(Lp[406]) - Lp[406] * tg[7];
    partials[gw] = val * (1.0f / 1024.0f);
  }
}

__global__ void k_reduce_final(const float* __restrict__ partials, float* __restrict__ out) {
  __shared__ float s[256];
  float v = 0.f;
  for (int i = threadIdx.x; i < 12288; i += 256) v += partials[i];
  s[threadIdx.x] = v;
  __syncthreads();
  for (int st = 128; st; st >>= 1) {
    if (threadIdx.x < st) s[threadIdx.x] += s[threadIdx.x + st];
    __syncthreads();
  }
  if (threadIdx.x == 0) out[0] = s[0];
}

// ---------------- launcher ----------------

extern "C" void kernel_launch(void* const* d_in, const int* in_sizes, int n_in,
                              void* d_out, int out_size, void* d_ws, size_t ws_size,
                              hipStream_t stream) {
  const float* obs      = (const float*)d_in[0];
  const float* actions  = (const float*)d_in[1];
  const float* beliefs  = (const float*)d_in[2];
  const float* w_ih     = (const float*)d_in[3];
  const float* w_hh     = (const float*)d_in[4];
  const float* b_ih     = (const float*)d_in[5];
  const float* b_hh     = (const float*)d_in[6];
  const float* pre_w1   = (const float*)d_in[7];
  const float* pre_b1   = (const float*)d_in[8];
  const float* pre_w2   = (const float*)d_in[9];
  const float* pre_b2   = (const float*)d_in[10];
  const float* dec_w    = (const float*)d_in[11];
  const float* dec_b    = (const float*)d_in[12];
  const int*   idx_i    = (const int*)d_in[13];
  const int*   Kmat     = (const int*)d_in[14];
  float* outF = (float*)d_out;

  char* p = (char*)d_ws;
  auto carve = [&](size_t bytes) {
    char* q = p;
    p += (bytes + 255) & ~(size_t)255;
    return q;
  };
  u8*   Wh8     = (u8*)carve(3072u * 1024u);
  bf16* Wib     = (bf16*)carve(3072u * 64u * 2u);
  bf16* actb    = (bf16*)carve(128u * 256u * 64u * 2u);
  bf16* preW1b  = (bf16*)carve(64u * 1024u * 2u);
  bf16* preW2b  = (bf16*)carve(1024u * 64u * 2u);
  bf16* decWb   = (bf16*)carve(814u * 1024u * 2u);
  u8*   hA8     = (u8*)carve(1536u * 1024u);
  u8*   hB8     = (u8*)carve(1536u * 1024u);
  bf16* states  = (bf16*)carve(6144u * 1024u * 2u);
  bf16* h1      = (bf16*)carve(6144u * 64u * 2u);
  bf16* xbuf    = (bf16*)carve(6144u * 1024u * 2u);
  float* logits = (float*)carve((size_t)6144u * 814u * 4u);
  float* partials = (float*)carve(12288u * 4u);

  k_prep<<<2048, 256, 0, stream>>>(w_hh, w_ih, actions, pre_w1, pre_w2, dec_w,
                                   beliefs, idx_i, Wh8, Wib, actb, preW1b, preW2b,
                                   decWb, hA8);

  for (int t = 0; t < 30; ++t) {
    const u8* hi8 = (t & 1) ? hB8 : hA8;
    u8* ho8 = (t & 1) ? hA8 : hB8;
    k_gru_step<<<512, 256, 0, stream>>>(hi8, ho8, Wh8, Wib, actb,
                                        b_ih, b_hh, idx_i, Kmat, states, t);
  }

  k_gemm_epi<0, 0><<<dim3(96, 1), 256, 0, stream>>>(states, preW1b, 1024, 64, 64,
                                                    pre_b1, nullptr, nullptr, h1);
  k_gemm_epi<1, 1><<<1536, 256, 0, stream>>>(h1, preW2b, 64, 1024, 1024,
                                             pre_b2, states, nullptr, xbuf);
  k_gemm_epi<2, 1><<<1248, 256, 0, stream>>>(xbuf, decWb, 1024, 814, 814,
                                             dec_b, nullptr, logits, nullptr);

  k_loss_wave<<<3072, 256, 0, stream>>>(logits, obs, idx_i, Kmat, partials);
  k_reduce_final<<<1, 256, 0, stream>>>(partials, outF);
}

// Round 19
// 534.908 us; speedup vs baseline: 2.1827x; 1.0008x over previous
//
#include <hip/hip_runtime.h>
#include <hip/hip_bf16.h>
#include <hip/hip_fp8.h>

typedef __bf16 bf16;
typedef unsigned char u8;
typedef __attribute__((ext_vector_type(4))) __bf16 bf16x4;
typedef __attribute__((ext_vector_type(8))) __bf16 bf16x8;
typedef __attribute__((ext_vector_type(4))) float f32x4;

static __device__ __forceinline__ f32x4 MFMA16(bf16x8 a, bf16x8 b, f32x4 c) {
  return __builtin_amdgcn_mfma_f32_16x16x32_bf16(a, b, c, 0, 0, 0);
}
static __device__ __forceinline__ f32x4 MFMA8(long a, long b, f32x4 c) {
  return __builtin_amdgcn_mfma_f32_16x16x32_fp8_fp8(a, b, c, 0, 0, 0);
}

__device__ __forceinline__ float sigm(float x) { return 1.0f / (1.0f + __expf(-x)); }
__device__ __forceinline__ float softplus_(float x) {
  return fmaxf(x, 0.0f) + log1pf(__expf(-fabsf(x)));
}
__device__ __forceinline__ u8 to_fp8(float x) {
  __hip_fp8_e4m3 v(x);
  return (u8)v.__x;
}
__device__ __forceinline__ float from_fp8(u8 b) {
  __hip_fp8_e4m3 v;
  v.__x = b;
  return (float)v;
}

__device__ __forceinline__ void gl16(const void* g, char* l) {
  __builtin_amdgcn_global_load_lds(
      (const __attribute__((address_space(1))) char*)g,
      (__attribute__((address_space(3))) char*)l, 16, 0, 0);
}

// ---------------- fused prep: conversions (bf16 + fp8) + h0(fp8) init ----------------
__global__ void k_prep(const float* __restrict__ whh, const float* __restrict__ wih,
                       const float* __restrict__ act, const float* __restrict__ w1,
                       const float* __restrict__ w2, const float* __restrict__ dw,
                       const float* __restrict__ beliefs, const int* __restrict__ idx_i,
                       u8* __restrict__ Wh8, bf16* __restrict__ Wib,
                       bf16* __restrict__ actb, bf16* __restrict__ w1b,
                       bf16* __restrict__ w2b, bf16* __restrict__ dwb,
                       u8* __restrict__ hA8) {
  for (int q = blockIdx.x * blockDim.x + threadIdx.x; q < 1994240;
       q += gridDim.x * blockDim.x) {
    if (q < 814592) {
      const float* src;
      bf16* dst;
      int off;
      if (q < 49152)       { src = wih; dst = Wib;  off = q; }
      else if (q < 573440) { src = act; dst = actb; off = q - 49152; }
      else if (q < 589824) { src = w1;  dst = w1b;  off = q - 573440; }
      else if (q < 606208) { src = w2;  dst = w2b;  off = q - 589824; }
      else                 { src = dw;  dst = dwb;  off = q - 606208; }
      float4 v = *(const float4*)&src[(size_t)off << 2];
      bf16x4 o = {(bf16)v.x, (bf16)v.y, (bf16)v.z, (bf16)v.w};
      *(bf16x4*)&dst[(size_t)off << 2] = o;
    } else if (q < 1207808) {
      const int e = (q - 814592) << 2;          // byte offset (1B/elem)
      const int n = e >> 18, rest = e & 262143;
      float4 v = *(const float4*)&beliefs[((size_t)idx_i[n] << 18) + rest];
      unsigned w = (unsigned)to_fp8(v.x) | ((unsigned)to_fp8(v.y) << 8) |
                   ((unsigned)to_fp8(v.z) << 16) | ((unsigned)to_fp8(v.w) << 24);
      const int par = (e >> 10) & 1;            // row (m) parity
      *(unsigned*)&hA8[e ^ (par << 3)] = w;
    } else {
      const int off = q - 1207808;
      float4 v = *(const float4*)&whh[(size_t)off << 2];
      unsigned w = (unsigned)to_fp8(v.x) | ((unsigned)to_fp8(v.y) << 8) |
                   ((unsigned)to_fp8(v.z) << 16) | ((unsigned)to_fp8(v.w) << 24);
      const int bo = off << 2;
      const int par = (bo >> 10) & 1;
      *(unsigned*)&Wh8[bo ^ (par << 3)] = w;
    }
  }
}

// ---------------- GRU step v13: v12 with 2-buffer LDS -> 3 blocks/CU ----------------
// Trade 2-ahead prefetch depth for occupancy (12 waves/CU): TLP covers both
// steady-state staging latency AND post-launch cold-L2 misses (which prefetch
// depth inside one block cannot). LDS 48KB/block, launch_bounds(256,3).
__global__ __launch_bounds__(256, 3) void k_gru_step(
    const u8* __restrict__ hin8, u8* __restrict__ hout8,
    const u8* __restrict__ Wh8, const bf16* __restrict__ Wib,
    const bf16* __restrict__ actb,
    const float* __restrict__ b_ih, const float* __restrict__ b_hh,
    const int* __restrict__ idx_i, const int* __restrict__ Kmat,
    bf16* __restrict__ states, int step) {
  const int pid = blockIdx.x;
  const int xcd = pid & 7;
  const int rg = xcd >> 2;
  const int cgp = xcd & 3;
  const int q = pid >> 3;
  const int mtl = q & 7;
  const int jtl = q >> 3;
  const int m0 = rg * 768 + mtl * 96;
  const int j0 = (cgp * 8 + jtl) * 32;

  {
    const int nlo = m0 >> 8, nhi = (m0 + 95) >> 8;
    int mk = max(max(Kmat[nlo * 4 + 0], Kmat[nlo * 4 + 1]),
                 max(Kmat[nlo * 4 + 2], Kmat[nlo * 4 + 3]));
    if (nhi != nlo)
      mk = max(mk, max(max(Kmat[nhi * 4 + 0], Kmat[nhi * 4 + 1]),
                       max(Kmat[nhi * 4 + 2], Kmat[nhi * 4 + 3])));
    if (step > mk) return;
  }

  const int tid = threadIdx.x, wave = tid >> 6, lane = tid & 63;
  const int l15 = lane & 15;
  const int kgrp = lane >> 4;
  const int wm = wave >> 1;
  const int wj = wave & 1;
  const int jlane = j0 + wj * 16 + l15;

  __shared__ alignas(16) char As[2 * 12288];
  __shared__ alignas(16) char Bs[2 * 12288];

  const int srow = lane >> 3;
  int a8off[3], b8off[3], aioff[3], bioff[3];
#pragma unroll
  for (int i = 0; i < 3; ++i) {
    const int r = wave * 24 + i * 8 + srow;
    const int grow = m0 + r;
    a8off[i] = grow * 1024 + ((((lane & 7) ^ ((r >> 1) & 7)) << 4));
    const int wr = (r >> 5) * 1024 + j0 + (r & 31);
    b8off[i] = wr * 1024 + ((((lane & 7) ^ ((r >> 1) & 7)) << 4));
    const int scol = (((lane & 7) ^ srow) << 3);
    const int np = grow >> 8;
    aioff[i] = ((idx_i[np] + step) * 256 + (grow & 255)) * 64 + scol;
    bioff[i] = wr * 64 + scol;
  }

  auto stage = [&](int buf, int slot) {
    char* ad = As + buf * 12288 + (wave * 24) * 128;
    char* bd = Bs + buf * 12288 + (wave * 24) * 128;
    if (slot < 8) {
#pragma unroll
      for (int i = 0; i < 3; ++i) {
        gl16(hin8 + a8off[i] + slot * 128, ad + i * 1024);
        gl16(Wh8 + b8off[i] + slot * 128, bd + i * 1024);
      }
    } else {
#pragma unroll
      for (int i = 0; i < 3; ++i) {
        gl16(actb + aioff[i], ad + i * 1024);
        gl16(Wib + bioff[i], bd + i * 1024);
      }
    }
  };

  f32x4 accR[3], accZ[3], accNh[3], accNi[3];
  const f32x4 zero = {0.f, 0.f, 0.f, 0.f};
#pragma unroll
  for (int f = 0; f < 3; ++f) { accR[f] = zero; accZ[f] = zero; accNh[f] = zero; accNi[f] = zero; }

  const float br = b_ih[jlane] + b_hh[jlane];
  const float bz = b_ih[1024 + jlane] + b_hh[1024 + jlane];
  const float bin = b_ih[2048 + jlane];
  const float bhn = b_hh[2048 + jlane];

  const int keyA = ((wm * 48 + l15) >> 1) & 7;
  const int keyB = ((wj * 16 + l15) >> 1) & 7;
  const int pa = (l15 & 1) << 3;   // parity half-swap bit

  auto computeF8 = [&](int buf) {
    const char* ab = As + buf * 12288;
    const char* bb = Bs + buf * 12288;
    const int ra = wm * 48 + l15;
    const int rb = wj * 16 + l15;
#pragma unroll
    for (int kkI = 0; kkI < 4; ++kkI) {
      const int hi = kkI * 2 + (kgrp >> 1);
      const int lo = (kgrp & 1) << 3;
      const int offA = ((((hi ^ keyA) << 4) | lo) ^ pa);
      const int offB = ((((hi ^ keyB) << 4) | lo) ^ pa);
      long a0 = *(const long*)(ab + ra * 128 + offA);
      long a1 = *(const long*)(ab + (ra + 16) * 128 + offA);
      long a2 = *(const long*)(ab + (ra + 32) * 128 + offA);
      long b0 = *(const long*)(bb + rb * 128 + offB);
      long b1 = *(const long*)(bb + (rb + 32) * 128 + offB);
      long b2 = *(const long*)(bb + (rb + 64) * 128 + offB);
      accR[0] = MFMA8(a0, b0, accR[0]);
      accR[1] = MFMA8(a1, b0, accR[1]);
      accR[2] = MFMA8(a2, b0, accR[2]);
      accZ[0] = MFMA8(a0, b1, accZ[0]);
      accZ[1] = MFMA8(a1, b1, accZ[1]);
      accZ[2] = MFMA8(a2, b1, accZ[2]);
      accNh[0] = MFMA8(a0, b2, accNh[0]);
      accNh[1] = MFMA8(a1, b2, accNh[1]);
      accNh[2] = MFMA8(a2, b2, accNh[2]);
    }
  };

  auto computeGi = [&](int buf) {
    const char* ab = As + buf * 12288;
    const char* bb = Bs + buf * 12288;
#pragma unroll
    for (int kkI = 0; kkI < 2; ++kkI) {
      const int kbyte = (((kkI << 5) + (kgrp << 3)) << 1) ^ ((l15 & 7) << 4);
      bf16x8 a0 = *(const bf16x8*)(ab + (wm * 48 + l15) * 128 + kbyte);
      bf16x8 a1 = *(const bf16x8*)(ab + (wm * 48 + 16 + l15) * 128 + kbyte);
      bf16x8 a2 = *(const bf16x8*)(ab + (wm * 48 + 32 + l15) * 128 + kbyte);
      bf16x8 b_r = *(const bf16x8*)(bb + (wj * 16 + l15) * 128 + kbyte);
      bf16x8 b_z = *(const bf16x8*)(bb + (32 + wj * 16 + l15) * 128 + kbyte);
      bf16x8 b_n = *(const bf16x8*)(bb + (64 + wj * 16 + l15) * 128 + kbyte);
      accR[0] = MFMA16(a0, b_r, accR[0]);
      accR[1] = MFMA16(a1, b_r, accR[1]);
      accR[2] = MFMA16(a2, b_r, accR[2]);
      accZ[0] = MFMA16(a0, b_z, accZ[0]);
      accZ[1] = MFMA16(a1, b_z, accZ[1]);
      accZ[2] = MFMA16(a2, b_z, accZ[2]);
      accNi[0] = MFMA16(a0, b_n, accNi[0]);
      accNi[1] = MFMA16(a1, b_n, accNi[1]);
      accNi[2] = MFMA16(a2, b_n, accNi[2]);
    }
  };

  stage(0, 0);   // 1-ahead double buffer

  unsigned hp8reg[3];

#pragma unroll
  for (int t = 0; t < 9; ++t) {
    if (t < 8) stage((t + 1) & 1, t + 1);
    if (t == 6) {
      // hp prefetch from fp8 h (L2-hot), un-swizzling parity swap
#pragma unroll
      for (int it2 = 0; it2 < 3; ++it2) {
        const int u = it2 * 256 + tid;
        const int row = u >> 3, c = u & 7;
        const int cs = c ^ ((row & 1) << 1);
        hp8reg[it2] =
            *(const unsigned*)(hin8 + (size_t)(m0 + row) * 1024 + j0 + cs * 4);
      }
    }
    // outstanding after issue: slot t+1 (6) [+ hp 3 from t>=6]
    if (t <= 5)       asm volatile("s_waitcnt vmcnt(6)" ::: "memory");
    else if (t <= 7)  asm volatile("s_waitcnt vmcnt(9)" ::: "memory");
    else              asm volatile("s_waitcnt vmcnt(0)" ::: "memory");
    __builtin_amdgcn_s_barrier();
    if (t == 8) computeGi(0);          // slot 8 staged into buf (8&1)=... buf 1? 8+... slot8 staged at t=7 into (7+1)&1=0
    else        computeF8(t & 1);
    __builtin_amdgcn_sched_barrier(0);
    __builtin_amdgcn_s_barrier();
  }

  // ---- epilogue: LDS transpose; fp8 h out (+ bf16 states when sampled) ----
  asm volatile("s_waitcnt vmcnt(0)" ::: "memory");   // hp8reg landed
  u8* Hp8 = (u8*)As;               // stride 40 B (buf0 dead after computeGi? buf0 holds slot8 -> done)
  bf16* Hn = (bf16*)Bs;            // stride 40 elems
  u8* Hn8 = (u8*)(As + 12288);     // buf1 (slot7, dead)

#pragma unroll
  for (int it2 = 0; it2 < 3; ++it2) {
    const int u = it2 * 256 + tid;
    const int row = u >> 3, c = u & 7;
    *(unsigned*)&Hp8[row * 40 + c * 4] = hp8reg[it2];   // logical order
  }
  __syncthreads();

#pragma unroll
  for (int mf = 0; mf < 3; ++mf) {
#pragma unroll
    for (int ii = 0; ii < 4; ++ii) {
      const int ml = wm * 48 + mf * 16 + kgrp * 4 + ii;
      const int jl = wj * 16 + l15;
      float hp = from_fp8(Hp8[ml * 40 + jl]);
      float rg2 = sigm(accR[mf][ii] + br);
      float zg = sigm(accZ[mf][ii] + bz);
      float ng = tanhf(accNi[mf][ii] + bin + rg2 * (accNh[mf][ii] + bhn));
      float hnew = (1.0f - zg) * ng + zg * hp;
      Hn[ml * 40 + jl] = (bf16)hnew;
      Hn8[ml * 40 + jl] = to_fp8(hnew);
    }
  }
  __syncthreads();

#pragma unroll
  for (int it2 = 0; it2 < 3; ++it2) {
    const int u = it2 * 256 + tid;
    const int row = u >> 3, c = u & 7;
    const int cs = c ^ ((row & 1) << 1);
    *(unsigned*)&hout8[(size_t)(m0 + row) * 1024 + j0 + cs * 4] =
        *(const unsigned*)&Hn8[row * 40 + c * 4];
    const int m = m0 + row;
    const int n = m >> 8;
    const int b = m & 255;
    uint2 v = *(const uint2*)&Hn[row * 40 + c * 4];
#pragma unroll
    for (int g = 0; g < 4; ++g) {
      if (Kmat[n * 4 + g] == step)
        *(uint2*)&states[((size_t)(n * 4 + g) * 256 + b) * 1024 + j0 + c * 4] = v;
    }
  }
}

// ---------------- generic GEMM: C = A(M x K) @ W(N x K)^T, fused epilogues ----------------
template <int EPI, int SWZ>
__global__ __launch_bounds__(256) void k_gemm_epi(
    const bf16* __restrict__ A, const bf16* __restrict__ W, int K, int Nreal, int ld_out,
    const float* __restrict__ bias, const bf16* __restrict__ resid,
    float* __restrict__ outF, bf16* __restrict__ outB) {
  int mt, jt;
  if (SWZ) {
    const int lin = blockIdx.x;
    const int x = lin & 7, k = lin >> 3;
    mt = 12 * x + k % 12;
    jt = k / 12;
  } else {
    mt = blockIdx.x;
    jt = blockIdx.y;
  }
  const int m0 = mt * 64;
  const int j0 = jt * 64;
  const int tid = threadIdx.x, wave = tid >> 6, lane = tid & 63;
  __shared__ alignas(16) bf16 Al[64][72];
  __shared__ alignas(16) bf16 Wl[64][72];

  f32x4 acc[4];
  const f32x4 zero = {0.f, 0.f, 0.f, 0.f};
#pragma unroll
  for (int f = 0; f < 4; ++f) acc[f] = zero;

  const int r = tid >> 3, c8 = (tid & 7) << 3;
  const int arow = wave * 16 + (lane & 15);
  const int koff = (lane >> 4) << 3;

  for (int kb = 0; kb < K; kb += 64) {
    *(bf16x8*)&Al[r][c8]      = *(const bf16x8*)&A[(size_t)(m0 + r) * K + kb + c8];
    *(bf16x8*)&Al[r + 32][c8] = *(const bf16x8*)&A[(size_t)(m0 + r + 32) * K + kb + c8];
    int jr = j0 + r;      if (jr >= Nreal) jr = Nreal - 1;
    int jr2 = j0 + r + 32; if (jr2 >= Nreal) jr2 = Nreal - 1;
    *(bf16x8*)&Wl[r][c8]      = *(const bf16x8*)&W[(size_t)jr * K + kb + c8];
    *(bf16x8*)&Wl[r + 32][c8] = *(const bf16x8*)&W[(size_t)jr2 * K + kb + c8];
    __syncthreads();
#pragma unroll
    for (int kk = 0; kk < 64; kk += 32) {
      bf16x8 av = *(const bf16x8*)&Al[arow][kk + koff];
#pragma unroll
      for (int nf = 0; nf < 4; ++nf) {
        acc[nf] = MFMA16(av, *(const bf16x8*)&Wl[nf * 16 + (lane & 15)][kk + koff], acc[nf]);
      }
    }
    __syncthreads();
  }

#pragma unroll
  for (int nf = 0; nf < 4; ++nf) {
    int j = j0 + nf * 16 + (lane & 15);
    float bj = (j < Nreal) ? bias[j] : 0.f;
#pragma unroll
    for (int i = 0; i < 4; ++i) {
      int m = m0 + wave * 16 + ((lane >> 4) << 2) + i;
      float v = acc[nf][i] + bj;
      if (EPI == 0) {
        outB[(size_t)m * ld_out + j] = (bf16)fmaxf(v, 0.f);
      } else if (EPI == 1) {
        v = fmaxf(v, 0.f) + (float)resid[(size_t)m * ld_out + j];
        outB[(size_t)m * ld_out + j] = (bf16)v;
      } else {
        if (j < Nreal) outF[(size_t)m * ld_out + j] = v;
      }
    }
  }
}

// ---------------- loss: one wave per (row, player-head) ----------------
__global__ __launch_bounds__(256) void k_loss_wave(
    const float* __restrict__ logits, const float* __restrict__ obs,
    const int* __restrict__ idx_i, const int* __restrict__ Kmat,
    float* __restrict__ partials) {
  const int gw = blockIdx.x * 4 + (threadIdx.x >> 6);
  const int lane = threadIdx.x & 63;
  const int row = gw >> 1, p = gw & 1;
  const int n = row >> 10, g = (row >> 8) & 3, b = row & 255;
  const int i = idx_i[n], k = Kmat[n * 4 + g];
  const float* Lp = logits + (size_t)row * 814 + p * 407;
  const float* tg = obs + ((size_t)(k + i + 1) * 256 + b) * 16 + p * 8;

  float v[7];
#pragma unroll
  for (int it = 0; it < 7; ++it) {
    const int c = lane + it * 64;
    v[it] = (c < 400) ? Lp[c] : -1e30f;
  }
  float mx = fmaxf(fmaxf(fmaxf(v[0], v[1]), fmaxf(v[2], v[3])),
                   fmaxf(fmaxf(v[4], v[5]), v[6]));
#pragma unroll
  for (int s = 32; s; s >>= 1) mx = fmaxf(mx, __shfl_xor(mx, s));
  float se = 0.f;
#pragma unroll
  for (int it = 0; it < 7; ++it) {
    const int c = lane + it * 64;
    se += (c < 400) ? __expf(v[it] - mx) : 0.f;
  }
#pragma unroll
  for (int s = 32; s; s >>= 1) se += __shfl_xor(se, s);

  if (lane == 0) {
    const int cls = (int)tg[0];
    float val = mx + logf(se) - Lp[cls];
    const float d0 = Lp[400] - tg[1], d1 = Lp[401] - tg[2];
    val += 0.5f * (d0 * d0 + d1 * d1);
    const float s2 = softplus_(Lp[402]) - tg[3]; val += s2 * s2;
    const float s3 = softplus_(Lp[403]) - tg[4]; val += s3 * s3;
    val += softplus_(Lp[404]) - Lp[404] * tg[5];
    val += softplus_(Lp[405]) - Lp[405] * tg[6];
    val += softplus_(Lp[406]) - Lp[406] * tg[7];
    partials[gw] = val * (1.0f / 1024.0f);
  }
}

__global__ void k_reduce_final(const float* __restrict__ partials, float* __restrict__ out) {
  __shared__ float s[256];
  float v = 0.f;
  for (int i = threadIdx.x; i < 12288; i += 256) v += partials[i];
  s[threadIdx.x] = v;
  __syncthreads();
  for (int st = 128; st; st >>= 1) {
    if (threadIdx.x < st) s[threadIdx.x] += s[threadIdx.x + st];
    __syncthreads();
  }
  if (threadIdx.x == 0) out[0] = s[0];
}

// ---------------- launcher ----------------

extern "C" void kernel_launch(void* const* d_in, const int* in_sizes, int n_in,
                              void* d_out, int out_size, void* d_ws, size_t ws_size,
                              hipStream_t stream) {
  const float* obs      = (const float*)d_in[0];
  const float* actions  = (const float*)d_in[1];
  const float* beliefs  = (const float*)d_in[2];
  const float* w_ih     = (const float*)d_in[3];
  const float* w_hh     = (const float*)d_in[4];
  const float* b_ih     = (const float*)d_in[5];
  const float* b_hh     = (const float*)d_in[6];
  const float* pre_w1   = (const float*)d_in[7];
  const float* pre_b1   = (const float*)d_in[8];
  const float* pre_w2   = (const float*)d_in[9];
  const float* pre_b2   = (const float*)d_in[10];
  const float* dec_w    = (const float*)d_in[11];
  const float* dec_b    = (const float*)d_in[12];
  const int*   idx_i    = (const int*)d_in[13];
  const int*   Kmat     = (const int*)d_in[14];
  float* outF = (float*)d_out;

  char* p = (char*)d_ws;
  auto carve = [&](size_t bytes) {
    char* q = p;
    p += (bytes + 255) & ~(size_t)255;
    return q;
  };
  u8*   Wh8     = (u8*)carve(3072u * 1024u);
  bf16* Wib     = (bf16*)carve(3072u * 64u * 2u);
  bf16* actb    = (bf16*)carve(128u * 256u * 64u * 2u);
  bf16* preW1b  = (bf16*)carve(64u * 1024u * 2u);
  bf16* preW2b  = (bf16*)carve(1024u * 64u * 2u);
  bf16* decWb   = (bf16*)carve(814u * 1024u * 2u);
  u8*   hA8     = (u8*)carve(1536u * 1024u);
  u8*   hB8     = (u8*)carve(1536u * 1024u);
  bf16* states  = (bf16*)carve(6144u * 1024u * 2u);
  bf16* h1      = (bf16*)carve(6144u * 64u * 2u);
  bf16* xbuf    = (bf16*)carve(6144u * 1024u * 2u);
  float* logits = (float*)carve((size_t)6144u * 814u * 4u);
  float* partials = (float*)carve(12288u * 4u);

  k_prep<<<2048, 256, 0, stream>>>(w_hh, w_ih, actions, pre_w1, pre_w2, dec_w,
                                   beliefs, idx_i, Wh8, Wib, actb, preW1b, preW2b,
                                   decWb, hA8);

  for (int t = 0; t < 30; ++t) {
    const u8* hi8 = (t & 1) ? hB8 : hA8;
    u8* ho8 = (t & 1) ? hA8 : hB8;
    k_gru_step<<<512, 256, 0, stream>>>(hi8, ho8, Wh8, Wib, actb,
                                        b_ih, b_hh, idx_i, Kmat, states, t);
  }

  k_gemm_epi<0, 0><<<dim3(96, 1), 256, 0, stream>>>(states, preW1b, 1024, 64, 64,
                                                    pre_b1, nullptr, nullptr, h1);
  k_gemm_epi<1, 1><<<1536, 256, 0, stream>>>(h1, preW2b, 64, 1024, 1024,
                                             pre_b2, states, nullptr, xbuf);
  k_gemm_epi<2, 1><<<1248, 256, 0, stream>>>(xbuf, decWb, 1024, 814, 814,
                                             dec_b, nullptr, logits, nullptr);

  k_loss_wave<<<3072, 256, 0, stream>>>(logits, obs, idx_i, Kmat, partials);
  k_reduce_final<<<1, 256, 0, stream>>>(partials, outF);
}